// Round 1
// baseline (480.711 us; speedup 1.0000x reference)
//
#include <hip/hip_runtime.h>
#include <math.h>

#define L_SEQ   1024
#define DMODEL  1024
#define DINNER  2048
#define NHEADS  32
#define HDIM    64
#define DSTATE  128
#define RROT    32
#define NPROJ   4480
#define OFF_Z   0
#define OFF_X   2048
#define OFF_B   4096
#define OFF_C   4224
#define OFF_DT  4352
#define OFF_A   4384
#define OFF_TR  4416
#define OFF_ANG 4448
#define NCHUNK  16
#define CLEN    64
#define PIF     3.14159265358979323846f

__device__ __forceinline__ float softplusf(float x) {
  return (x > 20.f) ? x : log1pf(expf(x));
}

// ---------------------------------------------------------------------------
// GEMM: C[M][N] = A[M][K] . B[N][K]^T   (both row-major, dot over K)
// 64x64 tile, BK=16, 256 threads, 4x4 micro-tile. fp32.
// ---------------------------------------------------------------------------
__global__ __launch_bounds__(256) void gemm_rrt(
    const float* __restrict__ A, const float* __restrict__ B,
    float* __restrict__ C, int M, int N, int K) {
  __shared__ float As[16][72];
  __shared__ float Bs[16][72];
  const int bm = blockIdx.y * 64;
  const int bn = blockIdx.x * 64;
  const int tid = threadIdx.x;
  const int tm = (tid >> 4) << 2;     // 0..60
  const int tn = (tid & 15) << 2;     // 0..60
  const int lr = tid >> 2;            // 0..63
  const int lk = (tid & 3) << 2;      // 0,4,8,12

  float acc[4][4] = {{0.f}};
  const float* Ag = A + (size_t)(bm + lr) * K + lk;
  const float* Bg = B + (size_t)(bn + lr) * K + lk;

  for (int k0 = 0; k0 < K; k0 += 16) {
    float4 a4 = *(const float4*)(Ag + k0);
    float4 b4 = *(const float4*)(Bg + k0);
    __syncthreads();
    As[lk + 0][lr] = a4.x; As[lk + 1][lr] = a4.y;
    As[lk + 2][lr] = a4.z; As[lk + 3][lr] = a4.w;
    Bs[lk + 0][lr] = b4.x; Bs[lk + 1][lr] = b4.y;
    Bs[lk + 2][lr] = b4.z; Bs[lk + 3][lr] = b4.w;
    __syncthreads();
#pragma unroll
    for (int kk = 0; kk < 16; ++kk) {
      float4 av = *(const float4*)&As[kk][tm];
      float4 bv = *(const float4*)&Bs[kk][tn];
      float a[4] = {av.x, av.y, av.z, av.w};
      float b[4] = {bv.x, bv.y, bv.z, bv.w};
#pragma unroll
      for (int i = 0; i < 4; ++i)
#pragma unroll
        for (int j = 0; j < 4; ++j)
          acc[i][j] = fmaf(a[i], b[j], acc[i][j]);
    }
  }
#pragma unroll
  for (int i = 0; i < 4; ++i) {
    float4 o = {acc[i][0], acc[i][1], acc[i][2], acc[i][3]};
    *(float4*)&C[(size_t)(bm + tm + i) * N + bn + tn] = o;
  }
}

// ---------------------------------------------------------------------------
// prep1: per (l,h): dt, alpha; per (l,h,p): G = beta*x[l-1] + gamma*x[l]
// idx = (l*32 + h)*64 + p
// ---------------------------------------------------------------------------
__global__ __launch_bounds__(256) void prep1(
    const float* __restrict__ proj, const float* __restrict__ dt_bias,
    float* __restrict__ G, float* __restrict__ dtA, float* __restrict__ alphaA) {
  const int idx = blockIdx.x * 256 + threadIdx.x;   // < 1024*32*64 = 2097152
  const int p = idx & 63;
  const int h = (idx >> 6) & 31;
  const int l = idx >> 11;
  const float* prow = proj + (size_t)l * NPROJ;

  float dt = softplusf(prow[OFF_DT + h] + dt_bias[h]);
  float Aneg = -fmaxf(softplusf(prow[OFF_A + h]), 1e-4f);
  float tr = 1.f / (1.f + expf(-prow[OFF_TR + h]));
  float alpha = expf(Aneg * dt);
  float beta = (1.f - tr) * dt * alpha;
  float gamma = tr * dt;

  float x = prow[OFF_X + h * HDIM + p];
  float px = (l > 0) ? proj[(size_t)(l - 1) * NPROJ + OFF_X + h * HDIM + p] : 0.f;
  G[idx] = beta * px + gamma * x;
  if (p == 0) {
    dtA[l * NHEADS + h] = dt;
    alphaA[l * NHEADS + h] = alpha;
  }
}

// ---------------------------------------------------------------------------
// theta_scan: inclusive cumsum over L of tanh(angles[l,r])*dt[l,h]*pi,
// then rc=cos(theta), rs=sin(theta).  One block per (h,r) channel.
// ---------------------------------------------------------------------------
__global__ __launch_bounds__(256) void theta_scan(
    const float* __restrict__ proj, const float* __restrict__ dtA,
    float* __restrict__ rc, float* __restrict__ rs) {
  const int h = blockIdx.x >> 5;
  const int r = blockIdx.x & 31;
  const int tid = threadIdx.x;
  __shared__ float lds[256];

  float csum[4];
  float run = 0.f;
#pragma unroll
  for (int i = 0; i < 4; ++i) {
    int l = tid * 4 + i;
    float ang = proj[(size_t)l * NPROJ + OFF_ANG + r];
    run += tanhf(ang) * dtA[l * NHEADS + h] * PIF;
    csum[i] = run;
  }
  lds[tid] = run;
  __syncthreads();
  for (int off = 1; off < 256; off <<= 1) {
    float t = (tid >= off) ? lds[tid - off] : 0.f;
    __syncthreads();
    lds[tid] += t;
    __syncthreads();
  }
  float excl = lds[tid] - run;
#pragma unroll
  for (int i = 0; i < 4; ++i) {
    int l = tid * 4 + i;
    float th = excl + csum[i];
    size_t o = ((size_t)l * NHEADS + h) * RROT + r;
    rc[o] = cosf(th);
    rs[o] = sinf(th);
  }
}

// ---------------------------------------------------------------------------
// chunk_decay: adec[h*16+c] = prod of alpha over chunk c
// ---------------------------------------------------------------------------
__global__ __launch_bounds__(256) void chunk_decay(
    const float* __restrict__ alphaA, float* __restrict__ adec) {
  const int idx = blockIdx.x * 256 + threadIdx.x;
  if (idx >= NHEADS * NCHUNK) return;
  const int h = idx >> 4;
  const int c = idx & 15;
  float f = 1.f;
  for (int t = 0; t < CLEN; ++t) f *= alphaA[(c * CLEN + t) * NHEADS + h];
  adec[idx] = f;
}

// ---------------------------------------------------------------------------
// scan_chunk<WITH_Y>: block per (c,h), 256 threads = 64 p x 4 n-quarters.
// Thread owns 8 rotary (sr,si) pairs + 24 plain sr states.
// WITH_Y=false: zero init, write chunk-local final states to S.
// WITH_Y=true : read init (S holds inits after combine), emit yz.
// S layout: [c][h][p][160]  (0..127 = sr, 128..159 = si)
// ---------------------------------------------------------------------------
template <bool WITH_Y>
__global__ __launch_bounds__(256) void scan_chunk(
    const float* __restrict__ proj, const float* __restrict__ G,
    const float* __restrict__ alphaA, const float* __restrict__ rc,
    const float* __restrict__ rs, float* __restrict__ S,
    float* __restrict__ yz, const float* __restrict__ Dvec) {
  const int c = blockIdx.x >> 5;
  const int h = blockIdx.x & 31;
  const int tid = threadIdx.x;
  const int p = tid >> 2;
  const int nq = tid & 3;
  const int nr0 = nq * 8;        // rotary states n = nr0..nr0+7
  const int np0 = 32 + nq * 24;  // plain states

  float* Sb = S + ((size_t)(c * NHEADS + h) * HDIM + p) * 160;

  float srr[8], sir[8], srp[24];
  if (WITH_Y) {
#pragma unroll
    for (int i = 0; i < 8; ++i)  srr[i] = Sb[nr0 + i];
#pragma unroll
    for (int i = 0; i < 8; ++i)  sir[i] = Sb[128 + nr0 + i];
#pragma unroll
    for (int i = 0; i < 24; ++i) srp[i] = Sb[np0 + i];
  } else {
#pragma unroll
    for (int i = 0; i < 8; ++i)  { srr[i] = 0.f; sir[i] = 0.f; }
#pragma unroll
    for (int i = 0; i < 24; ++i) srp[i] = 0.f;
  }
  const float Dh = WITH_Y ? Dvec[h] : 0.f;

  for (int t = 0; t < CLEN; ++t) {
    const int l = c * CLEN + t;
    const float a = alphaA[l * NHEADS + h];
    const float g = G[((size_t)l * NHEADS + h) * HDIM + p];
    const float* prow = proj + (size_t)l * NPROJ;
    const float* rcl = rc + ((size_t)l * NHEADS + h) * RROT + nr0;
    const float* rsl = rs + ((size_t)l * NHEADS + h) * RROT + nr0;
    const float* Brot = prow + OFF_B + nr0;
    const float* Bpl  = prow + OFF_B + np0;
    float yp = 0.f;
#pragma unroll
    for (int i = 0; i < 8; ++i) {
      float base = Brot[i] * g;
      srr[i] = fmaf(srr[i], a, base * rcl[i]);
      sir[i] = fmaf(sir[i], a, base * rsl[i]);
      if (WITH_Y) {
        float Cr = prow[OFF_C + nr0 + i];
        yp = fmaf(fmaf(srr[i], rcl[i], sir[i] * rsl[i]), Cr, yp);
      }
    }
#pragma unroll
    for (int i = 0; i < 24; ++i) {
      srp[i] = fmaf(srp[i], a, Bpl[i] * g);
      if (WITH_Y) yp = fmaf(srp[i], prow[OFF_C + np0 + i], yp);
    }
    if (WITH_Y) {
      yp += __shfl_xor(yp, 1);
      yp += __shfl_xor(yp, 2);
      if (nq == 0) {
        float x = prow[OFF_X + h * HDIM + p];
        float z = prow[OFF_Z + h * HDIM + p];
        float silu = z / (1.f + expf(-z));
        yz[(size_t)l * DINNER + h * HDIM + p] = (yp + Dh * x) * silu;
      }
    }
  }
  if (!WITH_Y) {
#pragma unroll
    for (int i = 0; i < 8; ++i)  Sb[nr0 + i] = srr[i];
#pragma unroll
    for (int i = 0; i < 8; ++i)  Sb[128 + nr0 + i] = sir[i];
#pragma unroll
    for (int i = 0; i < 24; ++i) Sb[np0 + i] = srp[i];
  }
}

// ---------------------------------------------------------------------------
// combine: sequential over 16 chunks per (h,p,n) lane.
// On entry S[c] = chunk-local finals; on exit S[c] = init state for chunk c.
// ---------------------------------------------------------------------------
__global__ __launch_bounds__(256) void combine(
    float* __restrict__ S, const float* __restrict__ adec) {
  const int idx = blockIdx.x * 256 + threadIdx.x;  // < 32*64*160 = 327680
  if (idx >= NHEADS * HDIM * 160) return;
  const int n = idx % 160;
  const int rem = idx / 160;
  const int p = rem & 63;
  const int h = rem >> 6;
  float F = 0.f;
  for (int c = 0; c < NCHUNK; ++c) {
    size_t off = ((size_t)(c * NHEADS + h) * HDIM + p) * 160 + n;
    float s = S[off];
    S[off] = F;                       // init for chunk c = final of chunk c-1
    F = fmaf(F, adec[h * NCHUNK + c], s);
  }
}

// ---------------------------------------------------------------------------
extern "C" void kernel_launch(void* const* d_in, const int* in_sizes, int n_in,
                              void* d_out, int out_size, void* d_ws, size_t ws_size,
                              hipStream_t stream) {
  const float* u       = (const float*)d_in[0];   // 1024 x 1024
  const float* w_in    = (const float*)d_in[1];   // 4480 x 1024
  const float* w_out   = (const float*)d_in[2];   // 1024 x 2048
  const float* dt_bias = (const float*)d_in[3];   // 32
  const float* Dvec    = (const float*)d_in[4];   // 32
  float* out = (float*)d_out;                     // 1024 x 1024

  float* ws = (float*)d_ws;
  float* proj   = ws;                      // 1024*4480 = 4,587,520
  float* G      = proj   + (size_t)L_SEQ * NPROJ;          // 2,097,152
  float* dtA    = G      + (size_t)L_SEQ * NHEADS * HDIM;  // 32,768
  float* alphaA = dtA    + L_SEQ * NHEADS;                 // 32,768
  float* rcb    = alphaA + L_SEQ * NHEADS;                 // 1,048,576
  float* rsb    = rcb    + (size_t)L_SEQ * NHEADS * RROT;  // 1,048,576
  float* adec   = rsb    + (size_t)L_SEQ * NHEADS * RROT;  // 512
  float* S      = adec   + 512;                            // 16*32*64*160 = 5,242,880
  float* yz     = S      + (size_t)NCHUNK * NHEADS * HDIM * 160; // 2,097,152

  // 1. proj = u @ w_in^T        (M=1024, N=4480, K=1024)
  gemm_rrt<<<dim3(NPROJ / 64, L_SEQ / 64), 256, 0, stream>>>(
      u, w_in, proj, L_SEQ, NPROJ, DMODEL);

  // 2. per-step scalars + G
  prep1<<<(L_SEQ * NHEADS * HDIM) / 256, 256, 0, stream>>>(
      proj, dt_bias, G, dtA, alphaA);

  // 3. theta cumsum -> rc, rs
  theta_scan<<<NHEADS * RROT, 256, 0, stream>>>(proj, dtA, rcb, rsb);

  // 4. per-chunk decay products
  chunk_decay<<<2, 256, 0, stream>>>(alphaA, adec);

  // 5. chunk-local scan (zero init) -> S = chunk finals
  scan_chunk<false><<<NCHUNK * NHEADS, 256, 0, stream>>>(
      proj, G, alphaA, rcb, rsb, S, nullptr, nullptr);

  // 6. cross-chunk combine -> S = chunk inits
  combine<<<(NHEADS * HDIM * 160 + 255) / 256, 256, 0, stream>>>(S, adec);

  // 7. re-scan with inits, emit yz = (y + D*x) * silu(z)
  scan_chunk<true><<<NCHUNK * NHEADS, 256, 0, stream>>>(
      proj, G, alphaA, rcb, rsb, S, yz, Dvec);

  // 8. out = yz @ w_out^T       (M=1024, N=1024, K=2048)
  gemm_rrt<<<dim3(DMODEL / 64, L_SEQ / 64), 256, 0, stream>>>(
      yz, w_out, out, L_SEQ, DMODEL, DINNER);
}

// Round 2
// 378.926 us; speedup vs baseline: 1.2686x; 1.2686x over previous
//
#include <hip/hip_runtime.h>
#include <math.h>

#define L_SEQ   1024
#define DMODEL  1024
#define DINNER  2048
#define NHEADS  32
#define HDIM    64
#define DSTATE  128
#define RROT    32
#define NPROJ   4480
#define OFF_Z   0
#define OFF_X   2048
#define OFF_B   4096
#define OFF_C   4224
#define OFF_DT  4352
#define OFF_A   4384
#define OFF_TR  4416
#define OFF_ANG 4448
#define NCHUNK  16
#define CLEN    64
#define PIF     3.14159265358979323846f

typedef __attribute__((ext_vector_type(8))) short bf16x8;
typedef __attribute__((ext_vector_type(4))) float f32x4;
typedef unsigned int u32;
typedef unsigned short u16;

__device__ __forceinline__ float softplusf(float x) {
  return (x > 20.f) ? x : log1pf(expf(x));
}

__device__ __forceinline__ u16 f2bf(float f) {
  u32 u = __float_as_uint(f);
  u32 r = (u + 0x7FFFu + ((u >> 16) & 1u)) >> 16;
  return (u16)r;
}

// ---------------------------------------------------------------------------
// f32 -> bf16 (RNE), 8 elems/thread
// ---------------------------------------------------------------------------
__global__ __launch_bounds__(256) void cvt_bf16(
    const float* __restrict__ src, u16* __restrict__ dst, int n8) {
  int i = blockIdx.x * 256 + threadIdx.x;
  if (i >= n8) return;
  const float4* s4 = (const float4*)src;
  float4 a = s4[2 * i], b = s4[2 * i + 1];
  union { u16 h[8]; uint4 v; } o;
  o.h[0] = f2bf(a.x); o.h[1] = f2bf(a.y); o.h[2] = f2bf(a.z); o.h[3] = f2bf(a.w);
  o.h[4] = f2bf(b.x); o.h[5] = f2bf(b.y); o.h[6] = f2bf(b.z); o.h[7] = f2bf(b.w);
  ((uint4*)dst)[i] = o.v;
}

// ---------------------------------------------------------------------------
// bf16 MFMA GEMM: C[M][N] = A[M][K] . B[N][K]^T, fp32 accumulate/output.
// BMxBN tile, BK=32, 256 threads = 4 waves in 2x2 layout, 16x16x32 MFMA.
// LDS: (BM+BN) rows x 32 bf16 (64B rows), XOR slot-swizzle vs bank conflict.
// ---------------------------------------------------------------------------
template <int BM, int BN>
__global__ __launch_bounds__(256) void gemm_bf16(
    const u16* __restrict__ A, const u16* __restrict__ B,
    float* __restrict__ C, int N, int K) {
  constexpr int BK = 32;
  constexpr int WM = BM / 2, WN = BN / 2;
  constexpr int MF = WM / 16, NF = WN / 16;
  constexpr int ROWS = BM + BN;
  constexpr int ISS = ROWS / 64;   // 16B stage-loads per thread
  __shared__ u16 lds[ROWS * 32];

  const int bm = blockIdx.y * BM;
  const int bn = blockIdx.x * BN;
  const int tid = threadIdx.x;
  const int w = tid >> 6, lane = tid & 63;
  const int wr = w >> 1, wc = w & 1;

  // staging addresses: chunk = j*4+w covers 16 rows of 64B
  const u16* gptr[ISS];
  u32 woff[ISS];
#pragma unroll
  for (int j = 0; j < ISS; ++j) {
    int chunk = j * 4 + w;
    int row = chunk * 16 + (lane >> 2);
    int sl = lane & 3;                    // logical 16B k-slot (coalesced load)
    int ph = sl ^ ((row >> 1) & 3);       // physical LDS slot (swizzled)
    const u16* base = (row < BM) ? (A + (size_t)(bm + row) * K)
                                 : (B + (size_t)(bn + (row - BM)) * K);
    gptr[j] = base + sl * 8;
    woff[j] = (u32)(row * 64 + ph * 16);
  }

  // fragment read offsets (same swizzle)
  u32 aoff[MF], boff[NF];
  const int s = lane >> 4;
#pragma unroll
  for (int i = 0; i < MF; ++i) {
    int row = wr * WM + i * 16 + (lane & 15);
    aoff[i] = (u32)(row * 64 + ((s ^ ((row >> 1) & 3)) * 16));
  }
#pragma unroll
  for (int j2 = 0; j2 < NF; ++j2) {
    int row = BM + wc * WN + j2 * 16 + (lane & 15);
    boff[j2] = (u32)(row * 64 + ((s ^ ((row >> 1) & 3)) * 16));
  }

  f32x4 acc[MF][NF] = {};
  uint4 stg[ISS];
#pragma unroll
  for (int j = 0; j < ISS; ++j) stg[j] = *(const uint4*)(gptr[j]);

  char* ldsb = (char*)lds;
  const int iters = K / BK;
  for (int it = 0; it < iters; ++it) {
    __syncthreads();                       // previous compute done
#pragma unroll
    for (int j = 0; j < ISS; ++j) *(uint4*)(ldsb + woff[j]) = stg[j];
    __syncthreads();
    if (it + 1 < iters) {                  // prefetch next K-slab (in flight
#pragma unroll                             //  under the MFMA block below)
      for (int j = 0; j < ISS; ++j)
        stg[j] = *(const uint4*)(gptr[j] + (size_t)(it + 1) * BK);
    }
    bf16x8 af[MF], bfr[NF];
#pragma unroll
    for (int i = 0; i < MF; ++i) af[i] = *(const bf16x8*)(ldsb + aoff[i]);
#pragma unroll
    for (int j2 = 0; j2 < NF; ++j2) bfr[j2] = *(const bf16x8*)(ldsb + boff[j2]);
#pragma unroll
    for (int i = 0; i < MF; ++i)
#pragma unroll
      for (int j2 = 0; j2 < NF; ++j2)
        acc[i][j2] = __builtin_amdgcn_mfma_f32_16x16x32_bf16(
            af[i], bfr[j2], acc[i][j2], 0, 0, 0);
  }

  // epilogue: C/D layout col=lane&15, row=(lane>>4)*4+reg (HW-verified)
#pragma unroll
  for (int i = 0; i < MF; ++i) {
    int rb = bm + wr * WM + i * 16 + (lane >> 4) * 4;
#pragma unroll
    for (int j2 = 0; j2 < NF; ++j2) {
      int cb = bn + wc * WN + j2 * 16 + (lane & 15);
#pragma unroll
      for (int r = 0; r < 4; ++r)
        C[(size_t)(rb + r) * N + cb] = acc[i][j2][r];
    }
  }
}

// ---------------------------------------------------------------------------
// prep1: per (l,h): dt, alpha; per (l,h,p): G = beta*x[l-1] + gamma*x[l]
// ---------------------------------------------------------------------------
__global__ __launch_bounds__(256) void prep1(
    const float* __restrict__ proj, const float* __restrict__ dt_bias,
    float* __restrict__ G, float* __restrict__ dtA, float* __restrict__ alphaA) {
  const int idx = blockIdx.x * 256 + threadIdx.x;
  const int p = idx & 63;
  const int h = (idx >> 6) & 31;
  const int l = idx >> 11;
  const float* prow = proj + (size_t)l * NPROJ;

  float dt = softplusf(prow[OFF_DT + h] + dt_bias[h]);
  float Aneg = -fmaxf(softplusf(prow[OFF_A + h]), 1e-4f);
  float tr = 1.f / (1.f + expf(-prow[OFF_TR + h]));
  float alpha = expf(Aneg * dt);
  float beta = (1.f - tr) * dt * alpha;
  float gamma = tr * dt;

  float x = prow[OFF_X + h * HDIM + p];
  float px = (l > 0) ? proj[(size_t)(l - 1) * NPROJ + OFF_X + h * HDIM + p] : 0.f;
  G[idx] = beta * px + gamma * x;
  if (p == 0) {
    dtA[l * NHEADS + h] = dt;
    alphaA[l * NHEADS + h] = alpha;
  }
}

// ---------------------------------------------------------------------------
// theta_scan: cumsum over L of tanh(ang)*dt*pi -> rc=cos, rs=sin
// ---------------------------------------------------------------------------
__global__ __launch_bounds__(256) void theta_scan(
    const float* __restrict__ proj, const float* __restrict__ dtA,
    float* __restrict__ rc, float* __restrict__ rs) {
  const int h = blockIdx.x >> 5;
  const int r = blockIdx.x & 31;
  const int tid = threadIdx.x;
  __shared__ float ldssc[256];

  float csum[4];
  float run = 0.f;
#pragma unroll
  for (int i = 0; i < 4; ++i) {
    int l = tid * 4 + i;
    float ang = proj[(size_t)l * NPROJ + OFF_ANG + r];
    run += tanhf(ang) * dtA[l * NHEADS + h] * PIF;
    csum[i] = run;
  }
  ldssc[tid] = run;
  __syncthreads();
  for (int off = 1; off < 256; off <<= 1) {
    float t = (tid >= off) ? ldssc[tid - off] : 0.f;
    __syncthreads();
    ldssc[tid] += t;
    __syncthreads();
  }
  float excl = ldssc[tid] - run;
#pragma unroll
  for (int i = 0; i < 4; ++i) {
    int l = tid * 4 + i;
    float th = excl + csum[i];
    size_t o = ((size_t)l * NHEADS + h) * RROT + r;
    rc[o] = cosf(th);
    rs[o] = sinf(th);
  }
}

// ---------------------------------------------------------------------------
__global__ __launch_bounds__(256) void chunk_decay(
    const float* __restrict__ alphaA, float* __restrict__ adec) {
  const int idx = blockIdx.x * 256 + threadIdx.x;
  if (idx >= NHEADS * NCHUNK) return;
  const int h = idx >> 4;
  const int c = idx & 15;
  float f = 1.f;
  for (int t = 0; t < CLEN; ++t) f *= alphaA[(c * CLEN + t) * NHEADS + h];
  adec[idx] = f;
}

// ---------------------------------------------------------------------------
// scan_chunk<WITH_Y>: block per (c,h), 256 thr = 64 p x 4 n-quarters.
// WITH_Y=true emits yz as bf16 (feeds GEMM2 directly).
// ---------------------------------------------------------------------------
template <bool WITH_Y>
__global__ __launch_bounds__(256) void scan_chunk(
    const float* __restrict__ proj, const float* __restrict__ G,
    const float* __restrict__ alphaA, const float* __restrict__ rc,
    const float* __restrict__ rs, float* __restrict__ S,
    u16* __restrict__ yz, const float* __restrict__ Dvec) {
  const int c = blockIdx.x >> 5;
  const int h = blockIdx.x & 31;
  const int tid = threadIdx.x;
  const int p = tid >> 2;
  const int nq = tid & 3;
  const int nr0 = nq * 8;
  const int np0 = 32 + nq * 24;

  float* Sb = S + ((size_t)(c * NHEADS + h) * HDIM + p) * 160;

  float srr[8], sir[8], srp[24];
  if (WITH_Y) {
#pragma unroll
    for (int i = 0; i < 8; ++i)  srr[i] = Sb[nr0 + i];
#pragma unroll
    for (int i = 0; i < 8; ++i)  sir[i] = Sb[128 + nr0 + i];
#pragma unroll
    for (int i = 0; i < 24; ++i) srp[i] = Sb[np0 + i];
  } else {
#pragma unroll
    for (int i = 0; i < 8; ++i)  { srr[i] = 0.f; sir[i] = 0.f; }
#pragma unroll
    for (int i = 0; i < 24; ++i) srp[i] = 0.f;
  }
  const float Dh = WITH_Y ? Dvec[h] : 0.f;

  for (int t = 0; t < CLEN; ++t) {
    const int l = c * CLEN + t;
    const float a = alphaA[l * NHEADS + h];
    const float g = G[((size_t)l * NHEADS + h) * HDIM + p];
    const float* prow = proj + (size_t)l * NPROJ;
    const float* rcl = rc + ((size_t)l * NHEADS + h) * RROT + nr0;
    const float* rsl = rs + ((size_t)l * NHEADS + h) * RROT + nr0;
    const float* Brot = prow + OFF_B + nr0;
    const float* Bpl  = prow + OFF_B + np0;
    float yp = 0.f;
#pragma unroll
    for (int i = 0; i < 8; ++i) {
      float base = Brot[i] * g;
      srr[i] = fmaf(srr[i], a, base * rcl[i]);
      sir[i] = fmaf(sir[i], a, base * rsl[i]);
      if (WITH_Y) {
        float Cr = prow[OFF_C + nr0 + i];
        yp = fmaf(fmaf(srr[i], rcl[i], sir[i] * rsl[i]), Cr, yp);
      }
    }
#pragma unroll
    for (int i = 0; i < 24; ++i) {
      srp[i] = fmaf(srp[i], a, Bpl[i] * g);
      if (WITH_Y) yp = fmaf(srp[i], prow[OFF_C + np0 + i], yp);
    }
    if (WITH_Y) {
      yp += __shfl_xor(yp, 1);
      yp += __shfl_xor(yp, 2);
      if (nq == 0) {
        float x = prow[OFF_X + h * HDIM + p];
        float z = prow[OFF_Z + h * HDIM + p];
        float silu = z / (1.f + expf(-z));
        yz[(size_t)l * DINNER + h * HDIM + p] = f2bf((yp + Dh * x) * silu);
      }
    }
  }
  if (!WITH_Y) {
#pragma unroll
    for (int i = 0; i < 8; ++i)  Sb[nr0 + i] = srr[i];
#pragma unroll
    for (int i = 0; i < 8; ++i)  Sb[128 + nr0 + i] = sir[i];
#pragma unroll
    for (int i = 0; i < 24; ++i) Sb[np0 + i] = srp[i];
  }
}

// ---------------------------------------------------------------------------
// combine: sequential over 16 chunks per (h,p,n) lane; finals -> inits.
// ---------------------------------------------------------------------------
__global__ __launch_bounds__(256) void combine(
    float* __restrict__ S, const float* __restrict__ adec) {
  const int idx = blockIdx.x * 256 + threadIdx.x;
  if (idx >= NHEADS * HDIM * 160) return;
  const int n = idx % 160;
  const int rem = idx / 160;
  const int p = rem & 63;
  const int h = rem >> 6;
  float F = 0.f;
  for (int c = 0; c < NCHUNK; ++c) {
    size_t off = ((size_t)(c * NHEADS + h) * HDIM + p) * 160 + n;
    float sv = S[off];
    S[off] = F;
    F = fmaf(F, adec[h * NCHUNK + c], sv);
  }
}

// ---------------------------------------------------------------------------
extern "C" void kernel_launch(void* const* d_in, const int* in_sizes, int n_in,
                              void* d_out, int out_size, void* d_ws, size_t ws_size,
                              hipStream_t stream) {
  const float* u       = (const float*)d_in[0];   // 1024 x 1024
  const float* w_in    = (const float*)d_in[1];   // 4480 x 1024
  const float* w_out   = (const float*)d_in[2];   // 1024 x 2048
  const float* dt_bias = (const float*)d_in[3];   // 32
  const float* Dvec    = (const float*)d_in[4];   // 32
  float* out = (float*)d_out;                     // 1024 x 1024

  float* ws = (float*)d_ws;
  float* proj   = ws;                                       // 4,587,520 f
  float* G      = proj   + (size_t)L_SEQ * NPROJ;           // 2,097,152 f
  float* dtA    = G      + (size_t)L_SEQ * NHEADS * HDIM;   //    32,768 f
  float* alphaA = dtA    + L_SEQ * NHEADS;                  //    32,768 f
  float* rcb    = alphaA + L_SEQ * NHEADS;                  // 1,048,576 f
  float* rsb    = rcb    + (size_t)L_SEQ * NHEADS * RROT;   // 1,048,576 f
  float* adec   = rsb    + (size_t)L_SEQ * NHEADS * RROT;   //       512 f
  float* S      = adec   + 512;                             // 5,242,880 f
  u16*   yzb    = (u16*)(S + (size_t)NCHUNK * NHEADS * HDIM * 160); // 2,097,152 u16
  u16*   wob    = (u16*)((float*)yzb + 1048576);            // 2,097,152 u16
  // u_bf16 / w_in_bf16 live inside S (lifetimes disjoint: dead before scan)
  u16*   ub     = (u16*)S;                                  // 1,048,576 u16
  u16*   wib    = (u16*)(S + 524288);                       // 4,587,520 u16

  // 0. convert inputs to bf16
  cvt_bf16<<<(1048576 / 8 + 255) / 256, 256, 0, stream>>>(u, ub, 1048576 / 8);
  cvt_bf16<<<(4587520 / 8 + 255) / 256, 256, 0, stream>>>(w_in, wib, 4587520 / 8);
  cvt_bf16<<<(2097152 / 8 + 255) / 256, 256, 0, stream>>>(w_out, wob, 2097152 / 8);

  // 1. proj = u @ w_in^T   (M=1024, N=4480, K=1024)
  gemm_bf16<128, 128><<<dim3(NPROJ / 128, L_SEQ / 128), 256, 0, stream>>>(
      ub, wib, proj, NPROJ, DMODEL);

  // 2..7. scan pipeline (fp32)
  prep1<<<(L_SEQ * NHEADS * HDIM) / 256, 256, 0, stream>>>(proj, dt_bias, G, dtA, alphaA);
  theta_scan<<<NHEADS * RROT, 256, 0, stream>>>(proj, dtA, rcb, rsb);
  chunk_decay<<<2, 256, 0, stream>>>(alphaA, adec);
  scan_chunk<false><<<NCHUNK * NHEADS, 256, 0, stream>>>(
      proj, G, alphaA, rcb, rsb, S, nullptr, nullptr);
  combine<<<(NHEADS * HDIM * 160 + 255) / 256, 256, 0, stream>>>(S, adec);
  scan_chunk<true><<<NCHUNK * NHEADS, 256, 0, stream>>>(
      proj, G, alphaA, rcb, rsb, S, yzb, Dvec);

  // 8. out = yz @ w_out^T  (M=1024, N=1024, K=2048)
  gemm_bf16<64, 64><<<dim3(DMODEL / 64, L_SEQ / 64), 256, 0, stream>>>(
      yzb, wob, out, DMODEL, DINNER);
}

// Round 3
// 263.669 us; speedup vs baseline: 1.8232x; 1.4371x over previous
//
#include <hip/hip_runtime.h>
#include <math.h>

#define L_SEQ   1024
#define DMODEL  1024
#define DINNER  2048
#define NH      32
#define HD      64
#define NS      160     // augmented state dim = 32 rot-re + 32 rot-im + 96 plain
#define RR      32      // rotary dims
#define NPROJ   4480
#define OFF_Z   0
#define OFF_X   2048
#define OFF_B   4096
#define OFF_C   4224
#define OFF_DT  4352
#define OFF_A   4384
#define OFF_TR  4416
#define OFF_ANG 4448
#define NC      16
#define CL      64
#define PIF     3.14159265358979323846f

typedef __attribute__((ext_vector_type(8))) short bf16x8;
typedef __attribute__((ext_vector_type(4))) float f32x4;
typedef unsigned int u32;
typedef unsigned short u16;

__device__ __forceinline__ float softplusf(float x) {
  return (x > 20.f) ? x : log1pf(expf(x));
}
__device__ __forceinline__ u16 f2bf(float f) {
  u32 u = __float_as_uint(f);
  u32 r = (u + 0x7FFFu + ((u >> 16) & 1u)) >> 16;
  return (u16)r;
}
__device__ __forceinline__ float bf2f(u16 v) {
  return __uint_as_float(((u32)v) << 16);
}

// ---------------------------------------------------------------------------
// f32 -> bf16 (RNE), 8 elems/thread
// ---------------------------------------------------------------------------
__global__ __launch_bounds__(256) void cvt_bf16(
    const float* __restrict__ src, u16* __restrict__ dst, int n8) {
  int i = blockIdx.x * 256 + threadIdx.x;
  if (i >= n8) return;
  const float4* s4 = (const float4*)src;
  float4 a = s4[2 * i], b = s4[2 * i + 1];
  union { u16 h[8]; uint4 v; } o;
  o.h[0] = f2bf(a.x); o.h[1] = f2bf(a.y); o.h[2] = f2bf(a.z); o.h[3] = f2bf(a.w);
  o.h[4] = f2bf(b.x); o.h[5] = f2bf(b.y); o.h[6] = f2bf(b.z); o.h[7] = f2bf(b.w);
  ((uint4*)dst)[i] = o.v;
}

// ---------------------------------------------------------------------------
// bf16 MFMA GEMM: C[M][N] = A[M][K] . B[N][K]^T  (proven in round 2)
// ---------------------------------------------------------------------------
template <int BM, int BN>
__global__ __launch_bounds__(256) void gemm_bf16(
    const u16* __restrict__ A, const u16* __restrict__ B,
    float* __restrict__ C, int N, int K) {
  constexpr int BK = 32;
  constexpr int WM = BM / 2, WN = BN / 2;
  constexpr int MF = WM / 16, NF = WN / 16;
  constexpr int ROWS = BM + BN;
  constexpr int ISS = ROWS / 64;
  __shared__ u16 lds[ROWS * 32];

  const int bm = blockIdx.y * BM;
  const int bn = blockIdx.x * BN;
  const int tid = threadIdx.x;
  const int w = tid >> 6, lane = tid & 63;
  const int wr = w >> 1, wc = w & 1;

  const u16* gptr[ISS];
  u32 woff[ISS];
#pragma unroll
  for (int j = 0; j < ISS; ++j) {
    int chunk = j * 4 + w;
    int row = chunk * 16 + (lane >> 2);
    int sl = lane & 3;
    int ph = sl ^ ((row >> 1) & 3);
    const u16* base = (row < BM) ? (A + (size_t)(bm + row) * K)
                                 : (B + (size_t)(bn + (row - BM)) * K);
    gptr[j] = base + sl * 8;
    woff[j] = (u32)(row * 64 + ph * 16);
  }

  u32 aoff[MF], boff[NF];
  const int s = lane >> 4;
#pragma unroll
  for (int i = 0; i < MF; ++i) {
    int row = wr * WM + i * 16 + (lane & 15);
    aoff[i] = (u32)(row * 64 + ((s ^ ((row >> 1) & 3)) * 16));
  }
#pragma unroll
  for (int j2 = 0; j2 < NF; ++j2) {
    int row = BM + wc * WN + j2 * 16 + (lane & 15);
    boff[j2] = (u32)(row * 64 + ((s ^ ((row >> 1) & 3)) * 16));
  }

  f32x4 acc[MF][NF] = {};
  uint4 stg[ISS];
#pragma unroll
  for (int j = 0; j < ISS; ++j) stg[j] = *(const uint4*)(gptr[j]);

  char* ldsb = (char*)lds;
  const int iters = K / BK;
  for (int it = 0; it < iters; ++it) {
    __syncthreads();
#pragma unroll
    for (int j = 0; j < ISS; ++j) *(uint4*)(ldsb + woff[j]) = stg[j];
    __syncthreads();
    if (it + 1 < iters) {
#pragma unroll
      for (int j = 0; j < ISS; ++j)
        stg[j] = *(const uint4*)(gptr[j] + (size_t)(it + 1) * BK);
    }
    bf16x8 af[MF], bfr[NF];
#pragma unroll
    for (int i = 0; i < MF; ++i) af[i] = *(const bf16x8*)(ldsb + aoff[i]);
#pragma unroll
    for (int j2 = 0; j2 < NF; ++j2) bfr[j2] = *(const bf16x8*)(ldsb + boff[j2]);
#pragma unroll
    for (int i = 0; i < MF; ++i)
#pragma unroll
      for (int j2 = 0; j2 < NF; ++j2)
        acc[i][j2] = __builtin_amdgcn_mfma_f32_16x16x32_bf16(
            af[i], bfr[j2], acc[i][j2], 0, 0, 0);
  }
#pragma unroll
  for (int i = 0; i < MF; ++i) {
    int rb = bm + wr * WM + i * 16 + (lane >> 4) * 4;
#pragma unroll
    for (int j2 = 0; j2 < NF; ++j2) {
      int cb = bn + wc * WN + j2 * 16 + (lane & 15);
#pragma unroll
      for (int r = 0; r < 4; ++r)
        C[(size_t)(rb + r) * N + cb] = acc[i][j2][r];
    }
  }
}

// ---------------------------------------------------------------------------
// prep_scalars: per (l,h): dt, ln(alpha), beta, gamma
// ---------------------------------------------------------------------------
__global__ __launch_bounds__(256) void prep_scalars(
    const float* __restrict__ proj, const float* __restrict__ dt_bias,
    float* __restrict__ dtA, float* __restrict__ lnaA,
    float* __restrict__ betaA, float* __restrict__ gammaA) {
  int idx = blockIdx.x * 256 + threadIdx.x;   // l*32+h
  int h = idx & 31, l = idx >> 5;
  const float* prow = proj + (size_t)l * NPROJ;
  float dt = softplusf(prow[OFF_DT + h] + dt_bias[h]);
  float Apos = fmaxf(softplusf(prow[OFF_A + h]), 1e-4f);
  float tr = 1.f / (1.f + expf(-prow[OFF_TR + h]));
  float lna = -Apos * dt;
  float alpha = expf(lna);
  dtA[idx] = dt;
  lnaA[idx] = lna;
  betaA[idx] = (1.f - tr) * dt * alpha;
  gammaA[idx] = tr * dt;
}

// ---------------------------------------------------------------------------
// theta_scan: cumsum over L of tanh(ang)*dt*pi -> rc=cos, rs=sin  (global)
// ---------------------------------------------------------------------------
__global__ __launch_bounds__(256) void theta_scan(
    const float* __restrict__ proj, const float* __restrict__ dtA,
    float* __restrict__ rc, float* __restrict__ rs) {
  const int h = blockIdx.x >> 5;
  const int r = blockIdx.x & 31;
  const int tid = threadIdx.x;
  __shared__ float ldssc[256];

  float csum[4];
  float run = 0.f;
#pragma unroll
  for (int i = 0; i < 4; ++i) {
    int l = tid * 4 + i;
    float ang = proj[(size_t)l * NPROJ + OFF_ANG + r];
    run += tanhf(ang) * dtA[l * NH + h] * PIF;
    csum[i] = run;
  }
  ldssc[tid] = run;
  __syncthreads();
  for (int off = 1; off < 256; off <<= 1) {
    float t = (tid >= off) ? ldssc[tid - off] : 0.f;
    __syncthreads();
    ldssc[tid] += t;
    __syncthreads();
  }
  float excl = ldssc[tid] - run;
#pragma unroll
  for (int i = 0; i < 4; ++i) {
    int l = tid * 4 + i;
    float th = excl + csum[i];
    size_t o = ((size_t)l * NH + h) * RR + r;
    rc[o] = cosf(th);
    rs[o] = sinf(th);
  }
}

// ---------------------------------------------------------------------------
// prep_uvg: per (h,c) block builds:
//   U[h][l][160], V[h][l][160] bf16  (rot-folded C / B)
//   Gt[h][c][p][64] bf16             (G transposed via LDS)
//   cumA[h][l] (per-chunk inclusive cumsum of ln alpha), adec[h][c]
// ---------------------------------------------------------------------------
__global__ __launch_bounds__(256) void prep_uvg(
    const float* __restrict__ proj, const float* __restrict__ betaA,
    const float* __restrict__ gammaA, const float* __restrict__ lnaA,
    const float* __restrict__ rc, const float* __restrict__ rs,
    u16* __restrict__ U, u16* __restrict__ V, u16* __restrict__ Gt,
    float* __restrict__ cumA, float* __restrict__ adec) {
  const int h = blockIdx.x >> 4, c = blockIdx.x & 15;
  const int c0 = c * CL;
  const int tid = threadIdx.x;
  __shared__ float xs[65][64];
  __shared__ u16 Gb[64][66];
  __shared__ float bet[64], gam[64];

  // P0: stage x slice (rows l = c0-1 .. c0+63)
  for (int i = tid; i < 65 * 64; i += 256) {
    int r = i >> 6, col = i & 63;
    int l = c0 - 1 + r;
    xs[r][col] = (l >= 0) ? proj[(size_t)l * NPROJ + OFF_X + h * HD + col] : 0.f;
  }
  if (tid < 64) {
    bet[tid] = betaA[(c0 + tid) * NH + h];
    gam[tid] = gammaA[(c0 + tid) * NH + h];
  }
  __syncthreads();

  // P1: G[s][p] = beta*x_{l-1} + gamma*x_l -> Gb bf16
  {
    int ss = tid & 63, pq = tid >> 6;
#pragma unroll
    for (int j = 0; j < 16; ++j) {
      int p = pq * 16 + j;
      float g = bet[ss] * xs[ss][p] + gam[ss] * xs[ss + 1][p];
      Gb[ss][p] = f2bf(g);
    }
  }
  __syncthreads();

  // P2: transpose Gb -> Gt[h][c][p][64]
  if (tid < 64) {
    int p = tid;
    union { u16 hh[64]; uint4 q[8]; } row;
#pragma unroll
    for (int ss = 0; ss < 64; ++ss) row.hh[ss] = Gb[ss][p];
    uint4* dst = (uint4*)(Gt + (((size_t)h * NC + c) * HD + p) * CL);
#pragma unroll
    for (int q = 0; q < 8; ++q) dst[q] = row.q[q];
  }

  // P3: U, V rows
  {
    int ss = tid >> 2, nq = tid & 3;
    int l = c0 + ss;
    const float* prow = proj + (size_t)l * NPROJ;
    const float* rcl = rc + ((size_t)l * NH + h) * RR;
    const float* rsl = rs + ((size_t)l * NH + h) * RR;
    union { u16 hh[40]; uint4 q[5]; } uu, vv;
#pragma unroll
    for (int j = 0; j < 40; ++j) {
      int n = nq * 40 + j;
      int r = n & 31;
      float Bv, Cv;
      if (n < 64) {
        float rot = (n < RR) ? rcl[r] : rsl[r];
        Bv = prow[OFF_B + r] * rot;
        Cv = prow[OFF_C + r] * rot;
      } else {
        Bv = prow[OFF_B + n - 32];
        Cv = prow[OFF_C + n - 32];
      }
      uu.hh[j] = f2bf(Cv);
      vv.hh[j] = f2bf(Bv);
    }
    uint4* Ud = (uint4*)(U + ((size_t)h * L_SEQ + l) * NS + nq * 40);
    uint4* Vd = (uint4*)(V + ((size_t)h * L_SEQ + l) * NS + nq * 40);
#pragma unroll
    for (int q = 0; q < 5; ++q) { Ud[q] = uu.q[q]; Vd[q] = vv.q[q]; }
  }

  // P5: per-chunk inclusive cumsum of ln(alpha) via wave-0 shfl scan
  if (tid < 64) {
    float v = lnaA[(c0 + tid) * NH + h];
#pragma unroll
    for (int k = 1; k < 64; k <<= 1) {
      int src = tid - k;
      float o = __shfl(v, src < 0 ? 0 : src);
      if (tid >= k) v += o;
    }
    cumA[(size_t)h * L_SEQ + c0 + tid] = v;
    if (tid == 63) adec[h * NC + c] = expf(v);
  }
}

// ---------------------------------------------------------------------------
// passA: chunk-local final states  F[p,n] = sum_s w[s]*G[s,p]*V[s,n]
// A-operand = Gt*w rows p, B-operand = V^T rows n (transposed in LDS).
// Output S[c][h][p][160] fp32.
// ---------------------------------------------------------------------------
__global__ __launch_bounds__(256) void passA(
    const u16* __restrict__ V, const u16* __restrict__ Gt,
    const float* __restrict__ cumA, float* __restrict__ S) {
  const int c = blockIdx.x >> 5, h = blockIdx.x & 31;
  const int c0 = c * CL;
  const int tid = threadIdx.x;
  const int w = tid >> 6, lane = tid & 63;
  const int wr = w >> 1, wc = w & 1;          // wr: p-half, wc: n-half(80)
  const int fr = lane & 15, sl = lane >> 4;
  __shared__ u16 Vl[64][168];
  __shared__ u16 Vt[160][72];
  __shared__ u16 Gw[64][72];
  __shared__ float wsc[64];

  const u16* Vsrc = V + ((size_t)h * L_SEQ + c0) * NS;
  for (int i = tid; i < 64 * 20; i += 256) {
    int r = i / 20, ch = i % 20;
    *(uint4*)&Vl[r][ch * 8] = *(const uint4*)(Vsrc + (size_t)r * NS + ch * 8);
  }
  if (tid < 64) {
    float last = cumA[(size_t)h * L_SEQ + c0 + 63];
    wsc[tid] = expf(last - cumA[(size_t)h * L_SEQ + c0 + tid]);
  }
  __syncthreads();

  // transpose Vl -> Vt
  if (tid < 160) {
    int n = tid;
#pragma unroll
    for (int s2 = 0; s2 < 32; ++s2) {
      u32 lo = Vl[2 * s2][n], hi = Vl[2 * s2 + 1][n];
      *(u32*)&Vt[n][2 * s2] = lo | (hi << 16);
    }
  }
  // stage Gt scaled by w[s]
  {
    const u16* Gsrc = Gt + ((size_t)h * NC + c) * HD * CL;
    for (int i = tid; i < 64 * 8; i += 256) {
      int p = i >> 3, ch = i & 7;
      uint4 raw = *(const uint4*)(Gsrc + (size_t)p * CL + ch * 8);
      u16* rh = (u16*)&raw;
      union { u16 hh[8]; uint4 q; } o;
#pragma unroll
      for (int j = 0; j < 8; ++j)
        o.hh[j] = f2bf(bf2f(rh[j]) * wsc[ch * 8 + j]);
      *(uint4*)&Gw[p][ch * 8] = o.q;
    }
  }
  __syncthreads();

  f32x4 acc[2][5] = {};
#pragma unroll
  for (int ks = 0; ks < 2; ++ks) {
    bf16x8 a0 = *(const bf16x8*)&Gw[wr * 32 + fr][ks * 32 + sl * 8];
    bf16x8 a1 = *(const bf16x8*)&Gw[wr * 32 + 16 + fr][ks * 32 + sl * 8];
    bf16x8 bv[5];
#pragma unroll
    for (int fj = 0; fj < 5; ++fj)
      bv[fj] = *(const bf16x8*)&Vt[wc * 80 + fj * 16 + fr][ks * 32 + sl * 8];
#pragma unroll
    for (int fj = 0; fj < 5; ++fj) {
      acc[0][fj] = __builtin_amdgcn_mfma_f32_16x16x32_bf16(a0, bv[fj], acc[0][fj], 0, 0, 0);
      acc[1][fj] = __builtin_amdgcn_mfma_f32_16x16x32_bf16(a1, bv[fj], acc[1][fj], 0, 0, 0);
    }
  }
  float* Fb = S + (size_t)(c * NH + h) * HD * NS;
#pragma unroll
  for (int fi = 0; fi < 2; ++fi)
#pragma unroll
    for (int fj = 0; fj < 5; ++fj)
#pragma unroll
      for (int r = 0; r < 4; ++r) {
        int p = wr * 32 + fi * 16 + sl * 4 + r;
        int n = wc * 80 + fj * 16 + fr;
        Fb[(size_t)p * NS + n] = acc[fi][fj][r];
      }
}

// ---------------------------------------------------------------------------
// combine: sequential over 16 chunks per (h,p,n); finals -> inits. (round-1)
// ---------------------------------------------------------------------------
__global__ __launch_bounds__(256) void combine(
    float* __restrict__ S, const float* __restrict__ adec) {
  const int idx = blockIdx.x * 256 + threadIdx.x;
  if (idx >= NH * HD * NS) return;
  const int n = idx % NS;
  const int rem = idx / NS;
  const int p = rem & 63;
  const int h = rem >> 6;
  float F = 0.f;
  for (int c = 0; c < NC; ++c) {
    size_t off = ((size_t)(c * NH + h) * HD + p) * NS + n;
    float sv = S[off];
    S[off] = F;
    F = fmaf(F, adec[h * NC + c], sv);
  }
}

// ---------------------------------------------------------------------------
// passB: Y[t,p] = ecum[t]*(U@S0^T)[t,p] + sum_{s<=t} exp(cum_t-cum_s)*P1[t,s]*G[s,p]
// then yz = (Y + D*x)*silu(z) as bf16.
// ---------------------------------------------------------------------------
__global__ __launch_bounds__(256) void passB(
    const float* __restrict__ proj, const u16* __restrict__ U,
    const u16* __restrict__ V, const u16* __restrict__ Gt,
    const float* __restrict__ cumA, const float* __restrict__ S,
    const float* __restrict__ Dvec, u16* __restrict__ yz) {
  const int c = blockIdx.x >> 5, h = blockIdx.x & 31;
  const int c0 = c * CL;
  const int tid = threadIdx.x;
  const int w = tid >> 6, lane = tid & 63;
  const int wr = w >> 1, wc = w & 1;
  const int fr = lane & 15, sl = lane >> 4;
  __shared__ u16 Ul[64][168];
  __shared__ u16 BB[64][168];
  __shared__ u16 Ml[64][72];
  __shared__ u16 Gl[64][72];
  __shared__ float cums[64], ecum[64];

  // stage U
  const u16* Us = U + ((size_t)h * L_SEQ + c0) * NS;
  for (int i = tid; i < 1280; i += 256) {
    int r = i / 20, ch = i % 20;
    *(uint4*)&Ul[r][ch * 8] = *(const uint4*)(Us + (size_t)r * NS + ch * 8);
  }
  // stage S0 (fp32 -> bf16) into BB
  {
    const float* S0 = S + (size_t)(c * NH + h) * HD * NS;
    int r = tid >> 2, q4 = tid & 3;
#pragma unroll
    for (int i = 0; i < 10; ++i) {
      int ch = q4 * 10 + i;
      float4 f = *(const float4*)(S0 + (size_t)r * NS + ch * 4);
      u32 lo = (u32)f2bf(f.x) | ((u32)f2bf(f.y) << 16);
      u32 hi = (u32)f2bf(f.z) | ((u32)f2bf(f.w) << 16);
      *(u32*)&BB[r][ch * 4] = lo;
      *(u32*)&BB[r][ch * 4 + 2] = hi;
    }
  }
  if (tid < 64) {
    float cv = cumA[(size_t)h * L_SEQ + c0 + tid];
    cums[tid] = cv;
    ecum[tid] = expf(cv);
  }
  __syncthreads();

  // P2 = U @ S0^T  -> acc (t rows, p cols)
  f32x4 acc[2][2] = {};
#pragma unroll
  for (int ks = 0; ks < 5; ++ks) {
    bf16x8 a0 = *(const bf16x8*)&Ul[wr * 32 + fr][ks * 32 + sl * 8];
    bf16x8 a1 = *(const bf16x8*)&Ul[wr * 32 + 16 + fr][ks * 32 + sl * 8];
    bf16x8 b0 = *(const bf16x8*)&BB[wc * 32 + fr][ks * 32 + sl * 8];
    bf16x8 b1 = *(const bf16x8*)&BB[wc * 32 + 16 + fr][ks * 32 + sl * 8];
    acc[0][0] = __builtin_amdgcn_mfma_f32_16x16x32_bf16(a0, b0, acc[0][0], 0, 0, 0);
    acc[0][1] = __builtin_amdgcn_mfma_f32_16x16x32_bf16(a0, b1, acc[0][1], 0, 0, 0);
    acc[1][0] = __builtin_amdgcn_mfma_f32_16x16x32_bf16(a1, b0, acc[1][0], 0, 0, 0);
    acc[1][1] = __builtin_amdgcn_mfma_f32_16x16x32_bf16(a1, b1, acc[1][1], 0, 0, 0);
  }
  // scale by ecum[t]
#pragma unroll
  for (int fi = 0; fi < 2; ++fi)
#pragma unroll
    for (int fj = 0; fj < 2; ++fj)
#pragma unroll
      for (int r = 0; r < 4; ++r)
        acc[fi][fj][r] *= ecum[wr * 32 + fi * 16 + sl * 4 + r];
  __syncthreads();   // all waves done reading BB

  // stage V into BB, Gt into Gl
  const u16* Vs = V + ((size_t)h * L_SEQ + c0) * NS;
  for (int i = tid; i < 1280; i += 256) {
    int r = i / 20, ch = i % 20;
    *(uint4*)&BB[r][ch * 8] = *(const uint4*)(Vs + (size_t)r * NS + ch * 8);
  }
  const u16* Gs = Gt + ((size_t)h * NC + c) * HD * CL;
  for (int i = tid; i < 512; i += 256) {
    int p = i >> 3, ch = i & 7;
    *(uint4*)&Gl[p][ch * 8] = *(const uint4*)(Gs + (size_t)p * CL + ch * 8);
  }
  __syncthreads();

  // P1 = U @ V^T  (t rows, s cols)
  f32x4 pac[2][2] = {};
#pragma unroll
  for (int ks = 0; ks < 5; ++ks) {
    bf16x8 a0 = *(const bf16x8*)&Ul[wr * 32 + fr][ks * 32 + sl * 8];
    bf16x8 a1 = *(const bf16x8*)&Ul[wr * 32 + 16 + fr][ks * 32 + sl * 8];
    bf16x8 b0 = *(const bf16x8*)&BB[wc * 32 + fr][ks * 32 + sl * 8];
    bf16x8 b1 = *(const bf16x8*)&BB[wc * 32 + 16 + fr][ks * 32 + sl * 8];
    pac[0][0] = __builtin_amdgcn_mfma_f32_16x16x32_bf16(a0, b0, pac[0][0], 0, 0, 0);
    pac[0][1] = __builtin_amdgcn_mfma_f32_16x16x32_bf16(a0, b1, pac[0][1], 0, 0, 0);
    pac[1][0] = __builtin_amdgcn_mfma_f32_16x16x32_bf16(a1, b0, pac[1][0], 0, 0, 0);
    pac[1][1] = __builtin_amdgcn_mfma_f32_16x16x32_bf16(a1, b1, pac[1][1], 0, 0, 0);
  }
  // M[t,s] = (s<=t) ? exp(cum_t - cum_s) * P1 : 0
#pragma unroll
  for (int fi = 0; fi < 2; ++fi)
#pragma unroll
    for (int fj = 0; fj < 2; ++fj)
#pragma unroll
      for (int r = 0; r < 4; ++r) {
        int t = wr * 32 + fi * 16 + sl * 4 + r;
        int ss = wc * 32 + fj * 16 + fr;
        float m = (ss <= t) ? expf(cums[t] - cums[ss]) * pac[fi][fj][r] : 0.f;
        Ml[t][ss] = f2bf(m);
      }
  __syncthreads();

  // Y += M @ Gt^T
#pragma unroll
  for (int ks = 0; ks < 2; ++ks) {
    bf16x8 a0 = *(const bf16x8*)&Ml[wr * 32 + fr][ks * 32 + sl * 8];
    bf16x8 a1 = *(const bf16x8*)&Ml[wr * 32 + 16 + fr][ks * 32 + sl * 8];
    bf16x8 b0 = *(const bf16x8*)&Gl[wc * 32 + fr][ks * 32 + sl * 8];
    bf16x8 b1 = *(const bf16x8*)&Gl[wc * 32 + 16 + fr][ks * 32 + sl * 8];
    acc[0][0] = __builtin_amdgcn_mfma_f32_16x16x32_bf16(a0, b0, acc[0][0], 0, 0, 0);
    acc[0][1] = __builtin_amdgcn_mfma_f32_16x16x32_bf16(a0, b1, acc[0][1], 0, 0, 0);
    acc[1][0] = __builtin_amdgcn_mfma_f32_16x16x32_bf16(a1, b0, acc[1][0], 0, 0, 0);
    acc[1][1] = __builtin_amdgcn_mfma_f32_16x16x32_bf16(a1, b1, acc[1][1], 0, 0, 0);
  }

  // epilogue: yz = (Y + D*x) * silu(z)
  const float Dh = Dvec[h];
#pragma unroll
  for (int fi = 0; fi < 2; ++fi)
#pragma unroll
    for (int fj = 0; fj < 2; ++fj)
#pragma unroll
      for (int r = 0; r < 4; ++r) {
        int t = wr * 32 + fi * 16 + sl * 4 + r;
        int p = wc * 32 + fj * 16 + fr;
        int l = c0 + t;
        float x = proj[(size_t)l * NPROJ + OFF_X + h * HD + p];
        float z = proj[(size_t)l * NPROJ + OFF_Z + h * HD + p];
        float y = acc[fi][fj][r] + Dh * x;
        float sg = z / (1.f + expf(-z));
        yz[(size_t)l * DINNER + h * HD + p] = f2bf(y * sg);
      }
}

// ---------------------------------------------------------------------------
extern "C" void kernel_launch(void* const* d_in, const int* in_sizes, int n_in,
                              void* d_out, int out_size, void* d_ws, size_t ws_size,
                              hipStream_t stream) {
  const float* u       = (const float*)d_in[0];
  const float* w_in    = (const float*)d_in[1];
  const float* w_out   = (const float*)d_in[2];
  const float* dt_bias = (const float*)d_in[3];
  const float* Dvec    = (const float*)d_in[4];
  float* out = (float*)d_out;

  float* ws = (float*)d_ws;
  float* proj   = ws;                          // 4,587,520 f
  float* dtA    = proj + 4587520;              // 32768
  float* lnaA   = dtA + 32768;
  float* betaA  = lnaA + 32768;
  float* gammaA = betaA + 32768;
  float* cumA   = gammaA + 32768;
  float* adec   = cumA + 32768;                // 512
  float* Sbuf   = adec + 512;                  // 5,242,880 f
  u16*   Gtb    = (u16*)(Sbuf + 5242880);      // 2,097,152 u16
  u16*   Ubuf   = Gtb + 2097152;               // 5,242,880 u16
  u16*   Vbuf   = Ubuf + 5242880;              // 5,242,880 u16
  u16*   yzb    = Vbuf + 5242880;              // 2,097,152 u16
  // overlays in Sbuf (disjoint lifetimes):
  u16*   ub   = (u16*)Sbuf;                    // epoch 1 (until gemm1)
  u16*   wib  = ub + 1048576;
  float* rcb  = Sbuf;                          // epoch 2 (theta -> prep_uvg)
  float* rsb  = rcb + 1048576;
  u16*   wob  = (u16*)Sbuf;                    // epoch 4 (after passB)

  // 0. inputs -> bf16
  cvt_bf16<<<(1048576 / 8 + 255) / 256, 256, 0, stream>>>(u, ub, 1048576 / 8);
  cvt_bf16<<<(4587520 / 8 + 255) / 256, 256, 0, stream>>>(w_in, wib, 4587520 / 8);

  // 1. proj = u @ w_in^T
  gemm_bf16<128, 128><<<dim3(NPROJ / 128, L_SEQ / 128), 256, 0, stream>>>(
      ub, wib, proj, NPROJ, DMODEL);

  // 2. scalars
  prep_scalars<<<(L_SEQ * NH) / 256, 256, 0, stream>>>(
      proj, dt_bias, dtA, lnaA, betaA, gammaA);

  // 3. theta -> rc, rs
  theta_scan<<<NH * RR, 256, 0, stream>>>(proj, dtA, rcb, rsb);

  // 4. U, V, Gt, cums
  prep_uvg<<<NH * NC, 256, 0, stream>>>(
      proj, betaA, gammaA, lnaA, rcb, rsb, Ubuf, Vbuf, Gtb, cumA, adec);

  // 5. chunk-local finals
  passA<<<NC * NH, 256, 0, stream>>>(Vbuf, Gtb, cumA, Sbuf);

  // 6. cross-chunk combine
  combine<<<(NH * HD * NS + 255) / 256, 256, 0, stream>>>(Sbuf, adec);

  // 7. Y + gate -> yz bf16
  passB<<<NC * NH, 256, 0, stream>>>(
      proj, Ubuf, Vbuf, Gtb, cumA, Sbuf, Dvec, yzb);

  // 8. w_out -> bf16 (Sbuf region is dead now)
  cvt_bf16<<<(2097152 / 8 + 255) / 256, 256, 0, stream>>>(w_out, wob, 2097152 / 8);

  // 9. out = yz @ w_out^T
  gemm_bf16<64, 64><<<dim3(DMODEL / 64, L_SEQ / 64), 256, 0, stream>>>(
      yzb, wob, out, DMODEL, DINNER);
}

// Round 4
// 180.809 us; speedup vs baseline: 2.6587x; 1.4583x over previous
//
#include <hip/hip_runtime.h>
#include <math.h>

#define L_SEQ   1024
#define DMODEL  1024
#define DINNER  2048
#define NH      32
#define HD      64
#define NS      160     // augmented state dim = 32 rot-re + 32 rot-im + 96 plain
#define RR      32      // rotary dims
#define NPROJ   4480
#define OFF_Z   0
#define OFF_X   2048
#define OFF_B   4096
#define OFF_C   4224
#define OFF_DT  4352
#define OFF_A   4384
#define OFF_TR  4416
#define OFF_ANG 4448
#define NC      16
#define CL      64
#define PIF     3.14159265358979323846f

typedef __attribute__((ext_vector_type(8))) short bf16x8;
typedef __attribute__((ext_vector_type(4))) float f32x4;
typedef unsigned int u32;
typedef unsigned short u16;

__device__ __forceinline__ float softplusf(float x) {
  return (x > 20.f) ? x : log1pf(expf(x));
}
__device__ __forceinline__ u16 f2bf(float f) {
  u32 u = __float_as_uint(f);
  u32 r = (u + 0x7FFFu + ((u >> 16) & 1u)) >> 16;
  return (u16)r;
}
__device__ __forceinline__ float bf2f(u16 v) {
  return __uint_as_float(((u32)v) << 16);
}

// global->LDS direct DMA, 16B per lane. LDS dest = wave-uniform base + lane*16.
// Addrspace casts via uintptr round-trip (composable_kernel's shipped pattern;
// LLVM folds ptrtoint(addrspacecast) so the AS3 offset is recovered).
__device__ __forceinline__ void gload_lds16(const u16* g, u16* l) {
  __builtin_amdgcn_global_load_lds(
      (const __attribute__((address_space(1))) u32*)(unsigned long long)(const void*)g,
      (__attribute__((address_space(3))) u32*)(unsigned long long)(void*)l, 16, 0, 0);
}

// ---------------------------------------------------------------------------
// f32 -> bf16 (RNE), 8 elems/thread
// ---------------------------------------------------------------------------
__global__ __launch_bounds__(256) void cvt_bf16(
    const float* __restrict__ src, u16* __restrict__ dst, int n8) {
  int i = blockIdx.x * 256 + threadIdx.x;
  if (i >= n8) return;
  const float4* s4 = (const float4*)src;
  float4 a = s4[2 * i], b = s4[2 * i + 1];
  union { u16 h[8]; uint4 v; } o;
  o.h[0] = f2bf(a.x); o.h[1] = f2bf(a.y); o.h[2] = f2bf(a.z); o.h[3] = f2bf(a.w);
  o.h[4] = f2bf(b.x); o.h[5] = f2bf(b.y); o.h[6] = f2bf(b.z); o.h[7] = f2bf(b.w);
  ((uint4*)dst)[i] = o.v;
}

// ---------------------------------------------------------------------------
// bf16 MFMA GEMM, m97 structure: C[M][N] = A[M][K] . B[N][K]^T, fp32 out.
// BMxBN tile, BK=32, 256 thr = 4 waves (2x2). Linear LDS [rows][32] (64B rows),
// global_load_lds(16B) staging, 2-barrier K-loop, stage(k+1) under MFMA(k).
// ---------------------------------------------------------------------------
template <int BM, int BN>
__global__ __launch_bounds__(256) void gemm_bf16(
    const u16* __restrict__ A, const u16* __restrict__ B,
    float* __restrict__ C, int N, int K) {
  constexpr int BK = 32;
  constexpr int WM = BM / 2, WN = BN / 2;
  constexpr int MF = WM / 16, NF = WN / 16;
  constexpr int CA = BM / 64;    // gload calls per wave (A); each call = 16 rows
  constexpr int CB = BN / 64;
  __shared__ u16 lds[(BM + BN) * BK];

  const int bm = blockIdx.y * BM, bn = blockIdx.x * BN;
  const int tid = threadIdx.x, w = tid >> 6, lane = tid & 63;
  const int wr = w >> 1, wc = w & 1;
  const int fr = lane & 15, sl = lane >> 4;
  const int lrow = lane >> 2, lslot = (lane & 3) * 8;

  const u16* gA[CA]; u16* lA[CA];
#pragma unroll
  for (int j = 0; j < CA; ++j) {
    int ca = w * CA + j;
    gA[j] = A + (size_t)(bm + ca * 16 + lrow) * K + lslot;
    lA[j] = lds + ca * 512;                       // 512 u16 = 1 KB per call
  }
  const u16* gB[CB]; u16* lB[CB];
#pragma unroll
  for (int j = 0; j < CB; ++j) {
    int cb = w * CB + j;
    gB[j] = B + (size_t)(bn + cb * 16 + lrow) * K + lslot;
    lB[j] = lds + BM * 32 + cb * 512;
  }

  const u16* aptr[MF]; const u16* bptr[NF];
#pragma unroll
  for (int i = 0; i < MF; ++i)
    aptr[i] = lds + (wr * WM + i * 16 + fr) * 32 + sl * 8;
#pragma unroll
  for (int j = 0; j < NF; ++j)
    bptr[j] = lds + BM * 32 + (wc * WN + j * 16 + fr) * 32 + sl * 8;

  f32x4 acc[MF][NF] = {};
  const int iters = K / BK;

  // prologue: issue tile 0 loads (drained by first barrier)
#pragma unroll
  for (int j = 0; j < CA; ++j) gload_lds16(gA[j], lA[j]);
#pragma unroll
  for (int j = 0; j < CB; ++j) gload_lds16(gB[j], lB[j]);

  for (int it = 0; it < iters; ++it) {
    __syncthreads();              // compiler drains vmcnt here -> tile ready
    bf16x8 af[MF], bfv[NF];
#pragma unroll
    for (int i = 0; i < MF; ++i) af[i] = *(const bf16x8*)aptr[i];
#pragma unroll
    for (int j = 0; j < NF; ++j) bfv[j] = *(const bf16x8*)bptr[j];
    __syncthreads();              // all waves done reading before overwrite
    if (it + 1 < iters) {         // next tile in flight under the MFMAs
#pragma unroll
      for (int j = 0; j < CA; ++j) gload_lds16(gA[j] + (it + 1) * BK, lA[j]);
#pragma unroll
      for (int j = 0; j < CB; ++j) gload_lds16(gB[j] + (it + 1) * BK, lB[j]);
    }
#pragma unroll
    for (int i = 0; i < MF; ++i)
#pragma unroll
      for (int j = 0; j < NF; ++j)
        acc[i][j] = __builtin_amdgcn_mfma_f32_16x16x32_bf16(
            af[i], bfv[j], acc[i][j], 0, 0, 0);
  }

  // epilogue: C/D layout col=lane&15, row=(lane>>4)*4+reg (HW-verified)
#pragma unroll
  for (int i = 0; i < MF; ++i) {
    int rb = bm + wr * WM + i * 16 + sl * 4;
#pragma unroll
    for (int j = 0; j < NF; ++j) {
      int cb = bn + wc * WN + j * 16 + fr;
#pragma unroll
      for (int r = 0; r < 4; ++r)
        C[(size_t)(rb + r) * N + cb] = acc[i][j][r];
    }
  }
}

// ---------------------------------------------------------------------------
// prep_scalars: per (l,h): dt, ln(alpha), beta, gamma
// ---------------------------------------------------------------------------
__global__ __launch_bounds__(256) void prep_scalars(
    const float* __restrict__ proj, const float* __restrict__ dt_bias,
    float* __restrict__ dtA, float* __restrict__ lnaA,
    float* __restrict__ betaA, float* __restrict__ gammaA) {
  int idx = blockIdx.x * 256 + threadIdx.x;   // l*32+h
  int h = idx & 31, l = idx >> 5;
  const float* prow = proj + (size_t)l * NPROJ;
  float dt = softplusf(prow[OFF_DT + h] + dt_bias[h]);
  float Apos = fmaxf(softplusf(prow[OFF_A + h]), 1e-4f);
  float tr = 1.f / (1.f + expf(-prow[OFF_TR + h]));
  float lna = -Apos * dt;
  float alpha = expf(lna);
  dtA[idx] = dt;
  lnaA[idx] = lna;
  betaA[idx] = (1.f - tr) * dt * alpha;
  gammaA[idx] = tr * dt;
}

// ---------------------------------------------------------------------------
// theta_scan: cumsum over L of tanh(ang)*dt*pi -> rc=cos, rs=sin  (global)
// ---------------------------------------------------------------------------
__global__ __launch_bounds__(256) void theta_scan(
    const float* __restrict__ proj, const float* __restrict__ dtA,
    float* __restrict__ rc, float* __restrict__ rs) {
  const int h = blockIdx.x >> 5;
  const int r = blockIdx.x & 31;
  const int tid = threadIdx.x;
  __shared__ float ldssc[256];

  float csum[4];
  float run = 0.f;
#pragma unroll
  for (int i = 0; i < 4; ++i) {
    int l = tid * 4 + i;
    float ang = proj[(size_t)l * NPROJ + OFF_ANG + r];
    run += tanhf(ang) * dtA[l * NH + h] * PIF;
    csum[i] = run;
  }
  ldssc[tid] = run;
  __syncthreads();
  for (int off = 1; off < 256; off <<= 1) {
    float t = (tid >= off) ? ldssc[tid - off] : 0.f;
    __syncthreads();
    ldssc[tid] += t;
    __syncthreads();
  }
  float excl = ldssc[tid] - run;
#pragma unroll
  for (int i = 0; i < 4; ++i) {
    int l = tid * 4 + i;
    float th = excl + csum[i];
    size_t o = ((size_t)l * NH + h) * RR + r;
    rc[o] = cosf(th);
    rs[o] = sinf(th);
  }
}

// ---------------------------------------------------------------------------
// prep_uvg: per (h,c) block builds U,V (rot-folded C/B), Gt, cumA, adec
// ---------------------------------------------------------------------------
__global__ __launch_bounds__(256) void prep_uvg(
    const float* __restrict__ proj, const float* __restrict__ betaA,
    const float* __restrict__ gammaA, const float* __restrict__ lnaA,
    const float* __restrict__ rc, const float* __restrict__ rs,
    u16* __restrict__ U, u16* __restrict__ V, u16* __restrict__ Gt,
    float* __restrict__ cumA, float* __restrict__ adec) {
  const int h = blockIdx.x >> 4, c = blockIdx.x & 15;
  const int c0 = c * CL;
  const int tid = threadIdx.x;
  __shared__ float xs[65][64];
  __shared__ u16 Gb[64][66];
  __shared__ float bet[64], gam[64];

  for (int i = tid; i < 65 * 64; i += 256) {
    int r = i >> 6, col = i & 63;
    int l = c0 - 1 + r;
    xs[r][col] = (l >= 0) ? proj[(size_t)l * NPROJ + OFF_X + h * HD + col] : 0.f;
  }
  if (tid < 64) {
    bet[tid] = betaA[(c0 + tid) * NH + h];
    gam[tid] = gammaA[(c0 + tid) * NH + h];
  }
  __syncthreads();

  {
    int ss = tid & 63, pq = tid >> 6;
#pragma unroll
    for (int j = 0; j < 16; ++j) {
      int p = pq * 16 + j;
      float g = bet[ss] * xs[ss][p] + gam[ss] * xs[ss + 1][p];
      Gb[ss][p] = f2bf(g);
    }
  }
  __syncthreads();

  if (tid < 64) {
    int p = tid;
    union { u16 hh[64]; uint4 q[8]; } row;
#pragma unroll
    for (int ss = 0; ss < 64; ++ss) row.hh[ss] = Gb[ss][p];
    uint4* dst = (uint4*)(Gt + (((size_t)h * NC + c) * HD + p) * CL);
#pragma unroll
    for (int q = 0; q < 8; ++q) dst[q] = row.q[q];
  }

  {
    int ss = tid >> 2, nq = tid & 3;
    int l = c0 + ss;
    const float* prow = proj + (size_t)l * NPROJ;
    const float* rcl = rc + ((size_t)l * NH + h) * RR;
    const float* rsl = rs + ((size_t)l * NH + h) * RR;
    union { u16 hh[40]; uint4 q[5]; } uu, vv;
#pragma unroll
    for (int j = 0; j < 40; ++j) {
      int n = nq * 40 + j;
      int r = n & 31;
      float Bv, Cv;
      if (n < 64) {
        float rot = (n < RR) ? rcl[r] : rsl[r];
        Bv = prow[OFF_B + r] * rot;
        Cv = prow[OFF_C + r] * rot;
      } else {
        Bv = prow[OFF_B + n - 32];
        Cv = prow[OFF_C + n - 32];
      }
      uu.hh[j] = f2bf(Cv);
      vv.hh[j] = f2bf(Bv);
    }
    uint4* Ud = (uint4*)(U + ((size_t)h * L_SEQ + l) * NS + nq * 40);
    uint4* Vd = (uint4*)(V + ((size_t)h * L_SEQ + l) * NS + nq * 40);
#pragma unroll
    for (int q = 0; q < 5; ++q) { Ud[q] = uu.q[q]; Vd[q] = vv.q[q]; }
  }

  if (tid < 64) {
    float v = lnaA[(c0 + tid) * NH + h];
#pragma unroll
    for (int k = 1; k < 64; k <<= 1) {
      int src = tid - k;
      float o = __shfl(v, src < 0 ? 0 : src);
      if (tid >= k) v += o;
    }
    cumA[(size_t)h * L_SEQ + c0 + tid] = v;
    if (tid == 63) adec[h * NC + c] = expf(v);
  }
}

// ---------------------------------------------------------------------------
// passA: chunk-local finals  F[p,n] = sum_s w[s]*G[s,p]*V[s,n]
// ---------------------------------------------------------------------------
__global__ __launch_bounds__(256) void passA(
    const u16* __restrict__ V, const u16* __restrict__ Gt,
    const float* __restrict__ cumA, float* __restrict__ S) {
  const int c = blockIdx.x >> 5, h = blockIdx.x & 31;
  const int c0 = c * CL;
  const int tid = threadIdx.x;
  const int w = tid >> 6, lane = tid & 63;
  const int wr = w >> 1, wc = w & 1;
  const int fr = lane & 15, sl = lane >> 4;
  __shared__ u16 Vl[64][168];
  __shared__ u16 Vt[160][72];
  __shared__ u16 Gw[64][72];
  __shared__ float wsc[64];

  const u16* Vsrc = V + ((size_t)h * L_SEQ + c0) * NS;
  for (int i = tid; i < 64 * 20; i += 256) {
    int r = i / 20, ch = i % 20;
    *(uint4*)&Vl[r][ch * 8] = *(const uint4*)(Vsrc + (size_t)r * NS + ch * 8);
  }
  if (tid < 64) {
    float last = cumA[(size_t)h * L_SEQ + c0 + 63];
    wsc[tid] = expf(last - cumA[(size_t)h * L_SEQ + c0 + tid]);
  }
  __syncthreads();

  if (tid < 160) {
    int n = tid;
#pragma unroll
    for (int s2 = 0; s2 < 32; ++s2) {
      u32 lo = Vl[2 * s2][n], hi = Vl[2 * s2 + 1][n];
      *(u32*)&Vt[n][2 * s2] = lo | (hi << 16);
    }
  }
  {
    const u16* Gsrc = Gt + ((size_t)h * NC + c) * HD * CL;
    for (int i = tid; i < 64 * 8; i += 256) {
      int p = i >> 3, ch = i & 7;
      uint4 raw = *(const uint4*)(Gsrc + (size_t)p * CL + ch * 8);
      u16* rh = (u16*)&raw;
      union { u16 hh[8]; uint4 q; } o;
#pragma unroll
      for (int j = 0; j < 8; ++j)
        o.hh[j] = f2bf(bf2f(rh[j]) * wsc[ch * 8 + j]);
      *(uint4*)&Gw[p][ch * 8] = o.q;
    }
  }
  __syncthreads();

  f32x4 acc[2][5] = {};
#pragma unroll
  for (int ks = 0; ks < 2; ++ks) {
    bf16x8 a0 = *(const bf16x8*)&Gw[wr * 32 + fr][ks * 32 + sl * 8];
    bf16x8 a1 = *(const bf16x8*)&Gw[wr * 32 + 16 + fr][ks * 32 + sl * 8];
    bf16x8 bv[5];
#pragma unroll
    for (int fj = 0; fj < 5; ++fj)
      bv[fj] = *(const bf16x8*)&Vt[wc * 80 + fj * 16 + fr][ks * 32 + sl * 8];
#pragma unroll
    for (int fj = 0; fj < 5; ++fj) {
      acc[0][fj] = __builtin_amdgcn_mfma_f32_16x16x32_bf16(a0, bv[fj], acc[0][fj], 0, 0, 0);
      acc[1][fj] = __builtin_amdgcn_mfma_f32_16x16x32_bf16(a1, bv[fj], acc[1][fj], 0, 0, 0);
    }
  }
  float* Fb = S + (size_t)(c * NH + h) * HD * NS;
#pragma unroll
  for (int fi = 0; fi < 2; ++fi)
#pragma unroll
    for (int fj = 0; fj < 5; ++fj)
#pragma unroll
      for (int r = 0; r < 4; ++r) {
        int p = wr * 32 + fi * 16 + sl * 4 + r;
        int n = wc * 80 + fj * 16 + fr;
        Fb[(size_t)p * NS + n] = acc[fi][fj][r];
      }
}

// ---------------------------------------------------------------------------
// combine: sequential over 16 chunks per (h,p,n); finals -> inits.
// ---------------------------------------------------------------------------
__global__ __launch_bounds__(256) void combine(
    float* __restrict__ S, const float* __restrict__ adec) {
  const int idx = blockIdx.x * 256 + threadIdx.x;
  if (idx >= NH * HD * NS) return;
  const int n = idx % NS;
  const int rem = idx / NS;
  const int p = rem & 63;
  const int h = rem >> 6;
  float F = 0.f;
  for (int c = 0; c < NC; ++c) {
    size_t off = ((size_t)(c * NH + h) * HD + p) * NS + n;
    float sv = S[off];
    S[off] = F;
    F = fmaf(F, adec[h * NC + c], sv);
  }
}

// ---------------------------------------------------------------------------
// passB: Y = ecum*(U@S0^T) + tril(exp(cum_t-cum_s)*(U@V^T)) @ G; gate; bf16 out
// ---------------------------------------------------------------------------
__global__ __launch_bounds__(256) void passB(
    const float* __restrict__ proj, const u16* __restrict__ U,
    const u16* __restrict__ V, const u16* __restrict__ Gt,
    const float* __restrict__ cumA, const float* __restrict__ S,
    const float* __restrict__ Dvec, u16* __restrict__ yz) {
  const int c = blockIdx.x >> 5, h = blockIdx.x & 31;
  const int c0 = c * CL;
  const int tid = threadIdx.x;
  const int w = tid >> 6, lane = tid & 63;
  const int wr = w >> 1, wc = w & 1;
  const int fr = lane & 15, sl = lane >> 4;
  __shared__ u16 Ul[64][168];
  __shared__ u16 BB[64][168];
  __shared__ u16 Ml[64][72];
  __shared__ u16 Gl[64][72];
  __shared__ float cums[64], ecum[64];

  const u16* Us = U + ((size_t)h * L_SEQ + c0) * NS;
  for (int i = tid; i < 1280; i += 256) {
    int r = i / 20, ch = i % 20;
    *(uint4*)&Ul[r][ch * 8] = *(const uint4*)(Us + (size_t)r * NS + ch * 8);
  }
  {
    const float* S0 = S + (size_t)(c * NH + h) * HD * NS;
    int r = tid >> 2, q4 = tid & 3;
#pragma unroll
    for (int i = 0; i < 10; ++i) {
      int ch = q4 * 10 + i;
      float4 f = *(const float4*)(S0 + (size_t)r * NS + ch * 4);
      u32 lo = (u32)f2bf(f.x) | ((u32)f2bf(f.y) << 16);
      u32 hi = (u32)f2bf(f.z) | ((u32)f2bf(f.w) << 16);
      *(u32*)&BB[r][ch * 4] = lo;
      *(u32*)&BB[r][ch * 4 + 2] = hi;
    }
  }
  if (tid < 64) {
    float cv = cumA[(size_t)h * L_SEQ + c0 + tid];
    cums[tid] = cv;
    ecum[tid] = expf(cv);
  }
  __syncthreads();

  f32x4 acc[2][2] = {};
#pragma unroll
  for (int ks = 0; ks < 5; ++ks) {
    bf16x8 a0 = *(const bf16x8*)&Ul[wr * 32 + fr][ks * 32 + sl * 8];
    bf16x8 a1 = *(const bf16x8*)&Ul[wr * 32 + 16 + fr][ks * 32 + sl * 8];
    bf16x8 b0 = *(const bf16x8*)&BB[wc * 32 + fr][ks * 32 + sl * 8];
    bf16x8 b1 = *(const bf16x8*)&BB[wc * 32 + 16 + fr][ks * 32 + sl * 8];
    acc[0][0] = __builtin_amdgcn_mfma_f32_16x16x32_bf16(a0, b0, acc[0][0], 0, 0, 0);
    acc[0][1] = __builtin_amdgcn_mfma_f32_16x16x32_bf16(a0, b1, acc[0][1], 0, 0, 0);
    acc[1][0] = __builtin_amdgcn_mfma_f32_16x16x32_bf16(a1, b0, acc[1][0], 0, 0, 0);
    acc[1][1] = __builtin_amdgcn_mfma_f32_16x16x32_bf16(a1, b1, acc[1][1], 0, 0, 0);
  }
#pragma unroll
  for (int fi = 0; fi < 2; ++fi)
#pragma unroll
    for (int fj = 0; fj < 2; ++fj)
#pragma unroll
      for (int r = 0; r < 4; ++r)
        acc[fi][fj][r] *= ecum[wr * 32 + fi * 16 + sl * 4 + r];
  __syncthreads();

  const u16* Vs = V + ((size_t)h * L_SEQ + c0) * NS;
  for (int i = tid; i < 1280; i += 256) {
    int r = i / 20, ch = i % 20;
    *(uint4*)&BB[r][ch * 8] = *(const uint4*)(Vs + (size_t)r * NS + ch * 8);
  }
  const u16* Gs = Gt + ((size_t)h * NC + c) * HD * CL;
  for (int i = tid; i < 512; i += 256) {
    int p = i >> 3, ch = i & 7;
    *(uint4*)&Gl[p][ch * 8] = *(const uint4*)(Gs + (size_t)p * CL + ch * 8);
  }
  __syncthreads();

  f32x4 pac[2][2] = {};
#pragma unroll
  for (int ks = 0; ks < 5; ++ks) {
    bf16x8 a0 = *(const bf16x8*)&Ul[wr * 32 + fr][ks * 32 + sl * 8];
    bf16x8 a1 = *(const bf16x8*)&Ul[wr * 32 + 16 + fr][ks * 32 + sl * 8];
    bf16x8 b0 = *(const bf16x8*)&BB[wc * 32 + fr][ks * 32 + sl * 8];
    bf16x8 b1 = *(const bf16x8*)&BB[wc * 32 + 16 + fr][ks * 32 + sl * 8];
    pac[0][0] = __builtin_amdgcn_mfma_f32_16x16x32_bf16(a0, b0, pac[0][0], 0, 0, 0);
    pac[0][1] = __builtin_amdgcn_mfma_f32_16x16x32_bf16(a0, b1, pac[0][1], 0, 0, 0);
    pac[1][0] = __builtin_amdgcn_mfma_f32_16x16x32_bf16(a1, b0, pac[1][0], 0, 0, 0);
    pac[1][1] = __builtin_amdgcn_mfma_f32_16x16x32_bf16(a1, b1, pac[1][1], 0, 0, 0);
  }
#pragma unroll
  for (int fi = 0; fi < 2; ++fi)
#pragma unroll
    for (int fj = 0; fj < 2; ++fj)
#pragma unroll
      for (int r = 0; r < 4; ++r) {
        int t = wr * 32 + fi * 16 + sl * 4 + r;
        int ss = wc * 32 + fj * 16 + fr;
        float m = (ss <= t) ? expf(cums[t] - cums[ss]) * pac[fi][fj][r] : 0.f;
        Ml[t][ss] = f2bf(m);
      }
  __syncthreads();

#pragma unroll
  for (int ks = 0; ks < 2; ++ks) {
    bf16x8 a0 = *(const bf16x8*)&Ml[wr * 32 + fr][ks * 32 + sl * 8];
    bf16x8 a1 = *(const bf16x8*)&Ml[wr * 32 + 16 + fr][ks * 32 + sl * 8];
    bf16x8 b0 = *(const bf16x8*)&Gl[wc * 32 + fr][ks * 32 + sl * 8];
    bf16x8 b1 = *(const bf16x8*)&Gl[wc * 32 + 16 + fr][ks * 32 + sl * 8];
    acc[0][0] = __builtin_amdgcn_mfma_f32_16x16x32_bf16(a0, b0, acc[0][0], 0, 0, 0);
    acc[0][1] = __builtin_amdgcn_mfma_f32_16x16x32_bf16(a0, b1, acc[0][1], 0, 0, 0);
    acc[1][0] = __builtin_amdgcn_mfma_f32_16x16x32_bf16(a1, b0, acc[1][0], 0, 0, 0);
    acc[1][1] = __builtin_amdgcn_mfma_f32_16x16x32_bf16(a1, b1, acc[1][1], 0, 0, 0);
  }

  const float Dh = Dvec[h];
#pragma unroll
  for (int fi = 0; fi < 2; ++fi)
#pragma unroll
    for (int fj = 0; fj < 2; ++fj)
#pragma unroll
      for (int r = 0; r < 4; ++r) {
        int t = wr * 32 + fi * 16 + sl * 4 + r;
        int p = wc * 32 + fj * 16 + fr;
        int l = c0 + t;
        float x = proj[(size_t)l * NPROJ + OFF_X + h * HD + p];
        float z = proj[(size_t)l * NPROJ + OFF_Z + h * HD + p];
        float y = acc[fi][fj][r] + Dh * x;
        float sg = z / (1.f + expf(-z));
        yz[(size_t)l * DINNER + h * HD + p] = f2bf(y * sg);
      }
}

// ---------------------------------------------------------------------------
extern "C" void kernel_launch(void* const* d_in, const int* in_sizes, int n_in,
                              void* d_out, int out_size, void* d_ws, size_t ws_size,
                              hipStream_t stream) {
  const float* u       = (const float*)d_in[0];
  const float* w_in    = (const float*)d_in[1];
  const float* w_out   = (const float*)d_in[2];
  const float* dt_bias = (const float*)d_in[3];
  const float* Dvec    = (const float*)d_in[4];
  float* out = (float*)d_out;

  float* ws = (float*)d_ws;
  float* proj   = ws;                          // 4,587,520 f
  float* dtA    = proj + 4587520;              // 32768
  float* lnaA   = dtA + 32768;
  float* betaA  = lnaA + 32768;
  float* gammaA = betaA + 32768;
  float* cumA   = gammaA + 32768;
  float* adec   = cumA + 32768;                // 512
  float* Sbuf   = adec + 512;                  // 5,242,880 f
  u16*   Gtb    = (u16*)(Sbuf + 5242880);      // 2,097,152 u16
  u16*   Ubuf   = Gtb + 2097152;               // 5,242,880 u16
  u16*   Vbuf   = Ubuf + 5242880;              // 5,242,880 u16
  u16*   yzb    = Vbuf + 5242880;              // 2,097,152 u16
  // overlays in Sbuf (disjoint lifetimes):
  u16*   ub   = (u16*)Sbuf;                    // epoch 1 (until gemm1)
  u16*   wib  = ub + 1048576;
  float* rcb  = Sbuf;                          // epoch 2 (theta -> prep_uvg)
  float* rsb  = rcb + 1048576;
  u16*   wob  = (u16*)Sbuf;                    // epoch 4 (after passB)

  // 0. inputs -> bf16
  cvt_bf16<<<(1048576 / 8 + 255) / 256, 256, 0, stream>>>(u, ub, 1048576 / 8);
  cvt_bf16<<<(4587520 / 8 + 255) / 256, 256, 0, stream>>>(w_in, wib, 4587520 / 8);

  // 1. proj = u @ w_in^T
  gemm_bf16<128, 128><<<dim3(NPROJ / 128, L_SEQ / 128), 256, 0, stream>>>(
      ub, wib, proj, NPROJ, DMODEL);

  // 2. scalars
  prep_scalars<<<(L_SEQ * NH) / 256, 256, 0, stream>>>(
      proj, dt_bias, dtA, lnaA, betaA, gammaA);

  // 3. theta -> rc, rs
  theta_scan<<<NH * RR, 256, 0, stream>>>(proj, dtA, rcb, rsb);

  // 4. U, V, Gt, cums
  prep_uvg<<<NH * NC, 256, 0, stream>>>(
      proj, betaA, gammaA, lnaA, rcb, rsb, Ubuf, Vbuf, Gtb, cumA, adec);

  // 5. chunk-local finals
  passA<<<NC * NH, 256, 0, stream>>>(Vbuf, Gtb, cumA, Sbuf);

  // 6. cross-chunk combine
  combine<<<(NH * HD * NS + 255) / 256, 256, 0, stream>>>(Sbuf, adec);

  // 7. Y + gate -> yz bf16
  passB<<<NC * NH, 256, 0, stream>>>(
      proj, Ubuf, Vbuf, Gtb, cumA, Sbuf, Dvec, yzb);

  // 8. w_out -> bf16 (Sbuf region dead now)
  cvt_bf16<<<(2097152 / 8 + 255) / 256, 256, 0, stream>>>(w_out, wob, 2097152 / 8);

  // 9. out = yz @ w_out^T
  gemm_bf16<64, 64><<<dim3(DMODEL / 64, L_SEQ / 64), 256, 0, stream>>>(
      yzb, wob, out, DMODEL, DINNER);
}

// Round 5
// 150.651 us; speedup vs baseline: 3.1909x; 1.2002x over previous
//
#include <hip/hip_runtime.h>
#include <math.h>

#define L_SEQ   1024
#define DMODEL  1024
#define DINNER  2048
#define NH      32
#define HD      64
#define NS      160     // augmented state dim = 32 rot-re + 32 rot-im + 96 plain
#define RR      32      // rotary dims
#define NPROJ   4480
#define OFF_Z   0
#define OFF_X   2048
#define OFF_B   4096
#define OFF_C   4224
#define OFF_DT  4352
#define OFF_A   4384
#define OFF_TR  4416
#define OFF_ANG 4448
#define NC      16
#define CL      64
#define PIF     3.14159265358979323846f

typedef __attribute__((ext_vector_type(8))) short bf16x8;
typedef __attribute__((ext_vector_type(4))) float f32x4;
typedef unsigned int u32;
typedef unsigned short u16;

__device__ __forceinline__ float softplusf(float x) {
  return (x > 20.f) ? x : log1pf(expf(x));
}
__device__ __forceinline__ u16 f2bf(float f) {
  u32 u = __float_as_uint(f);
  u32 r = (u + 0x7FFFu + ((u >> 16) & 1u)) >> 16;
  return (u16)r;
}
__device__ __forceinline__ float bf2f(u16 v) {
  return __uint_as_float(((u32)v) << 16);
}

// global->LDS direct DMA, 16B per lane (m97 staging path).
__device__ __forceinline__ void gload_lds16(const u16* g, u16* l) {
  __builtin_amdgcn_global_load_lds(
      (const __attribute__((address_space(1))) u32*)(unsigned long long)(const void*)g,
      (__attribute__((address_space(3))) u32*)(unsigned long long)(void*)l, 16, 0, 0);
}

// ---------------------------------------------------------------------------
// f32 -> bf16 (RNE), 8 elems/thread
// ---------------------------------------------------------------------------
__global__ __launch_bounds__(256) void cvt_bf16(
    const float* __restrict__ src, u16* __restrict__ dst, int n8) {
  int i = blockIdx.x * 256 + threadIdx.x;
  if (i >= n8) return;
  const float4* s4 = (const float4*)src;
  float4 a = s4[2 * i], b = s4[2 * i + 1];
  union { u16 h[8]; uint4 v; } o;
  o.h[0] = f2bf(a.x); o.h[1] = f2bf(a.y); o.h[2] = f2bf(a.z); o.h[3] = f2bf(a.w);
  o.h[4] = f2bf(b.x); o.h[5] = f2bf(b.y); o.h[6] = f2bf(b.z); o.h[7] = f2bf(b.w);
  ((uint4*)dst)[i] = o.v;
}

// ---------------------------------------------------------------------------
// bf16 MFMA GEMM, m97 structure (round-4, verified): C = A . B^T, fp32 out.
// ---------------------------------------------------------------------------
template <int BM, int BN>
__global__ __launch_bounds__(256) void gemm_bf16(
    const u16* __restrict__ A, const u16* __restrict__ B,
    float* __restrict__ C, int N, int K) {
  constexpr int BK = 32;
  constexpr int WM = BM / 2, WN = BN / 2;
  constexpr int MF = WM / 16, NF = WN / 16;
  constexpr int CA = BM / 64;
  constexpr int CB = BN / 64;
  __shared__ u16 lds[(BM + BN) * BK];

  const int bm = blockIdx.y * BM, bn = blockIdx.x * BN;
  const int tid = threadIdx.x, w = tid >> 6, lane = tid & 63;
  const int wr = w >> 1, wc = w & 1;
  const int fr = lane & 15, sl = lane >> 4;
  const int lrow = lane >> 2, lslot = (lane & 3) * 8;

  const u16* gA[CA]; u16* lA[CA];
#pragma unroll
  for (int j = 0; j < CA; ++j) {
    int ca = w * CA + j;
    gA[j] = A + (size_t)(bm + ca * 16 + lrow) * K + lslot;
    lA[j] = lds + ca * 512;
  }
  const u16* gB[CB]; u16* lB[CB];
#pragma unroll
  for (int j = 0; j < CB; ++j) {
    int cb = w * CB + j;
    gB[j] = B + (size_t)(bn + cb * 16 + lrow) * K + lslot;
    lB[j] = lds + BM * 32 + cb * 512;
  }

  const u16* aptr[MF]; const u16* bptr[NF];
#pragma unroll
  for (int i = 0; i < MF; ++i)
    aptr[i] = lds + (wr * WM + i * 16 + fr) * 32 + sl * 8;
#pragma unroll
  for (int j = 0; j < NF; ++j)
    bptr[j] = lds + BM * 32 + (wc * WN + j * 16 + fr) * 32 + sl * 8;

  f32x4 acc[MF][NF] = {};
  const int iters = K / BK;

#pragma unroll
  for (int j = 0; j < CA; ++j) gload_lds16(gA[j], lA[j]);
#pragma unroll
  for (int j = 0; j < CB; ++j) gload_lds16(gB[j], lB[j]);

  for (int it = 0; it < iters; ++it) {
    __syncthreads();
    bf16x8 af[MF], bfv[NF];
#pragma unroll
    for (int i = 0; i < MF; ++i) af[i] = *(const bf16x8*)aptr[i];
#pragma unroll
    for (int j = 0; j < NF; ++j) bfv[j] = *(const bf16x8*)bptr[j];
    __syncthreads();
    if (it + 1 < iters) {
#pragma unroll
      for (int j = 0; j < CA; ++j) gload_lds16(gA[j] + (it + 1) * BK, lA[j]);
#pragma unroll
      for (int j = 0; j < CB; ++j) gload_lds16(gB[j] + (it + 1) * BK, lB[j]);
    }
#pragma unroll
    for (int i = 0; i < MF; ++i)
#pragma unroll
      for (int j = 0; j < NF; ++j)
        acc[i][j] = __builtin_amdgcn_mfma_f32_16x16x32_bf16(
            af[i], bfv[j], acc[i][j], 0, 0, 0);
  }

#pragma unroll
  for (int i = 0; i < MF; ++i) {
    int rb = bm + wr * WM + i * 16 + sl * 4;
#pragma unroll
    for (int j = 0; j < NF; ++j) {
      int cb = bn + wc * WN + j * 16 + fr;
#pragma unroll
      for (int r = 0; r < 4; ++r)
        C[(size_t)(rb + r) * N + cb] = acc[i][j][r];
    }
  }
}

// ---------------------------------------------------------------------------
// prep_scalars: per (l,h): dt, ln(alpha), beta, gamma; also angP = tanh(ang)*pi
// (h index doubles as rotary index r since RR == NH == 32)
// ---------------------------------------------------------------------------
__global__ __launch_bounds__(256) void prep_scalars(
    const float* __restrict__ proj, const float* __restrict__ dt_bias,
    float* __restrict__ dtA, float* __restrict__ lnaA,
    float* __restrict__ betaA, float* __restrict__ gammaA,
    float* __restrict__ angP) {
  int idx = blockIdx.x * 256 + threadIdx.x;   // l*32+h
  int h = idx & 31, l = idx >> 5;
  const float* prow = proj + (size_t)l * NPROJ;
  float dt = softplusf(prow[OFF_DT + h] + dt_bias[h]);
  float Apos = fmaxf(softplusf(prow[OFF_A + h]), 1e-4f);
  float tr = 1.f / (1.f + expf(-prow[OFF_TR + h]));
  float lna = -Apos * dt;
  float alpha = expf(lna);
  dtA[idx] = dt;
  lnaA[idx] = lna;
  betaA[idx] = (1.f - tr) * dt * alpha;
  gammaA[idx] = tr * dt;
  angP[idx] = tanhf(prow[OFF_ANG + h]) * PIF;
}

// ---------------------------------------------------------------------------
// theta_scan: cumsum over L of angP*dt -> rc=cos, rs=sin. Block per (h,r).
// angP/dtA are dense [l][32] -> full-line reads shared across blocks.
// ---------------------------------------------------------------------------
__global__ __launch_bounds__(256) void theta_scan(
    const float* __restrict__ angP, const float* __restrict__ dtA,
    float* __restrict__ rc, float* __restrict__ rs) {
  const int h = blockIdx.x >> 5;
  const int r = blockIdx.x & 31;
  const int tid = threadIdx.x;
  __shared__ float ldssc[256];

  float csum[4];
  float run = 0.f;
#pragma unroll
  for (int i = 0; i < 4; ++i) {
    int l = tid * 4 + i;
    run += angP[l * NH + r] * dtA[l * NH + h];
    csum[i] = run;
  }
  ldssc[tid] = run;
  __syncthreads();
  for (int off = 1; off < 256; off <<= 1) {
    float t = (tid >= off) ? ldssc[tid - off] : 0.f;
    __syncthreads();
    ldssc[tid] += t;
    __syncthreads();
  }
  float excl = ldssc[tid] - run;
#pragma unroll
  for (int i = 0; i < 4; ++i) {
    int l = tid * 4 + i;
    float th = excl + csum[i];
    size_t o = ((size_t)l * NH + h) * RR + r;
    rc[o] = cosf(th);
    rs[o] = sinf(th);
  }
}

// ---------------------------------------------------------------------------
// prep_uvg (rewritten): block per (h,c).
//  P0: vec-stage xs (rows c0-1..c0+63)
//  P1: Gt[p][s] built directly transposed (lane=p, wave=s-quarter)
//  P2: U/V lane-per-n (lanes 0..159; coalesced B/C/rc/rs reads + row stores)
//      wave 3 concurrently: cumA shfl-scan + adec
// ---------------------------------------------------------------------------
__global__ __launch_bounds__(256) void prep_uvg(
    const float* __restrict__ proj, const float* __restrict__ betaA,
    const float* __restrict__ gammaA, const float* __restrict__ lnaA,
    const float* __restrict__ rc, const float* __restrict__ rs,
    u16* __restrict__ U, u16* __restrict__ V, u16* __restrict__ Gt,
    float* __restrict__ cumA, float* __restrict__ adec) {
  const int h = blockIdx.x >> 4, c = blockIdx.x & 15;
  const int c0 = c * CL;
  const int tid = threadIdx.x;
  const int w = tid >> 6, lane = tid & 63;
  __shared__ float xs[65][64];
  __shared__ float bet[64], gam[64];

  // P0: stage x rows (float4, coalesced)
  for (int i = tid; i < 65 * 16; i += 256) {
    int r = i >> 4, c4 = i & 15;
    int l = c0 - 1 + r;
    float4 v = {0.f, 0.f, 0.f, 0.f};
    if (l >= 0)
      v = *(const float4*)(proj + (size_t)l * NPROJ + OFF_X + h * HD + c4 * 4);
    *(float4*)&xs[r][c4 * 4] = v;
  }
  if (tid < 64) {
    bet[tid] = betaA[(c0 + tid) * NH + h];
    gam[tid] = gammaA[(c0 + tid) * NH + h];
  }
  __syncthreads();

  // P1: Gt[p][s] — lane = p (row-contiguous xs reads, 2-way bank = free)
  {
    const int p = lane;
    union { u16 hh[16]; uint4 q[2]; } o;
    float xprev = xs[w * 16][p];
#pragma unroll
    for (int i = 0; i < 16; ++i) {
      int s = w * 16 + i;
      float xcur = xs[s + 1][p];
      o.hh[i] = f2bf(bet[s] * xprev + gam[s] * xcur);
      xprev = xcur;
    }
    uint4* dst = (uint4*)(Gt + (((size_t)h * NC + c) * HD + p) * CL + w * 16);
    dst[0] = o.q[0];
    dst[1] = o.q[1];
  }

  // P2: U/V rows, lane-per-n; wave 3 does the cumA scan
  if (tid < 160) {
    const int n = tid;
    const int idxB = (n < 64) ? (n & 31) : (n - 32);
    const bool is_re = (n < 32);
    const bool has_rot = (n < 64);
    for (int ss = 0; ss < 64; ++ss) {
      int l = c0 + ss;
      const float* prow = proj + (size_t)l * NPROJ;
      float Bv = prow[OFF_B + idxB];
      float Cv = prow[OFF_C + idxB];
      if (has_rot) {
        float rv = is_re ? rc[((size_t)l * NH + h) * RR + idxB]
                         : rs[((size_t)l * NH + h) * RR + idxB];
        Bv *= rv;
        Cv *= rv;
      }
      U[((size_t)h * L_SEQ + l) * NS + n] = f2bf(Cv);
      V[((size_t)h * L_SEQ + l) * NS + n] = f2bf(Bv);
    }
  } else if (tid >= 192) {
    const int t = tid - 192;     // lane within wave 3
    float v = lnaA[(c0 + t) * NH + h];
#pragma unroll
    for (int k = 1; k < 64; k <<= 1) {
      int src = t - k;
      float o = __shfl(v, src < 0 ? 0 : src);
      if (t >= k) v += o;
    }
    cumA[(size_t)h * L_SEQ + c0 + t] = v;
    if (t == 63) adec[h * NC + c] = expf(v);
  }
}

// ---------------------------------------------------------------------------
// passA: chunk-local finals  F[p,n] = sum_s w[s]*G[s,p]*V[s,n]
// ---------------------------------------------------------------------------
__global__ __launch_bounds__(256) void passA(
    const u16* __restrict__ V, const u16* __restrict__ Gt,
    const float* __restrict__ cumA, float* __restrict__ S) {
  const int c = blockIdx.x >> 5, h = blockIdx.x & 31;
  const int c0 = c * CL;
  const int tid = threadIdx.x;
  const int w = tid >> 6, lane = tid & 63;
  const int wr = w >> 1, wc = w & 1;
  const int fr = lane & 15, sl = lane >> 4;
  __shared__ u16 Vl[64][168];
  __shared__ u16 Vt[160][72];
  __shared__ u16 Gw[64][72];
  __shared__ float wsc[64];

  const u16* Vsrc = V + ((size_t)h * L_SEQ + c0) * NS;
  for (int i = tid; i < 64 * 20; i += 256) {
    int r = i / 20, ch = i % 20;
    *(uint4*)&Vl[r][ch * 8] = *(const uint4*)(Vsrc + (size_t)r * NS + ch * 8);
  }
  if (tid < 64) {
    float last = cumA[(size_t)h * L_SEQ + c0 + 63];
    wsc[tid] = expf(last - cumA[(size_t)h * L_SEQ + c0 + tid]);
  }
  __syncthreads();

  if (tid < 160) {
    int n = tid;
#pragma unroll
    for (int s2 = 0; s2 < 32; ++s2) {
      u32 lo = Vl[2 * s2][n], hi = Vl[2 * s2 + 1][n];
      *(u32*)&Vt[n][2 * s2] = lo | (hi << 16);
    }
  }
  {
    const u16* Gsrc = Gt + ((size_t)h * NC + c) * HD * CL;
    for (int i = tid; i < 64 * 8; i += 256) {
      int p = i >> 3, ch = i & 7;
      uint4 raw = *(const uint4*)(Gsrc + (size_t)p * CL + ch * 8);
      u16* rh = (u16*)&raw;
      union { u16 hh[8]; uint4 q; } o;
#pragma unroll
      for (int j = 0; j < 8; ++j)
        o.hh[j] = f2bf(bf2f(rh[j]) * wsc[ch * 8 + j]);
      *(uint4*)&Gw[p][ch * 8] = o.q;
    }
  }
  __syncthreads();

  f32x4 acc[2][5] = {};
#pragma unroll
  for (int ks = 0; ks < 2; ++ks) {
    bf16x8 a0 = *(const bf16x8*)&Gw[wr * 32 + fr][ks * 32 + sl * 8];
    bf16x8 a1 = *(const bf16x8*)&Gw[wr * 32 + 16 + fr][ks * 32 + sl * 8];
    bf16x8 bv[5];
#pragma unroll
    for (int fj = 0; fj < 5; ++fj)
      bv[fj] = *(const bf16x8*)&Vt[wc * 80 + fj * 16 + fr][ks * 32 + sl * 8];
#pragma unroll
    for (int fj = 0; fj < 5; ++fj) {
      acc[0][fj] = __builtin_amdgcn_mfma_f32_16x16x32_bf16(a0, bv[fj], acc[0][fj], 0, 0, 0);
      acc[1][fj] = __builtin_amdgcn_mfma_f32_16x16x32_bf16(a1, bv[fj], acc[1][fj], 0, 0, 0);
    }
  }
  float* Fb = S + (size_t)(c * NH + h) * HD * NS;
#pragma unroll
  for (int fi = 0; fi < 2; ++fi)
#pragma unroll
    for (int fj = 0; fj < 5; ++fj)
#pragma unroll
      for (int r = 0; r < 4; ++r) {
        int p = wr * 32 + fi * 16 + sl * 4 + r;
        int n = wc * 80 + fj * 16 + fr;
        Fb[(size_t)p * NS + n] = acc[fi][fj][r];
      }
}

// ---------------------------------------------------------------------------
// combine: sequential over 16 chunks per (h,p,n); finals -> inits.
// ---------------------------------------------------------------------------
__global__ __launch_bounds__(256) void combine(
    float* __restrict__ S, const float* __restrict__ adec) {
  const int idx = blockIdx.x * 256 + threadIdx.x;
  if (idx >= NH * HD * NS) return;
  const int n = idx % NS;
  const int rem = idx / NS;
  const int p = rem & 63;
  const int h = rem >> 6;
  float F = 0.f;
  for (int c = 0; c < NC; ++c) {
    size_t off = ((size_t)(c * NH + h) * HD + p) * NS + n;
    float sv = S[off];
    S[off] = F;
    F = fmaf(F, adec[h * NC + c], sv);
  }
}

// ---------------------------------------------------------------------------
// passB: Y = ecum*(U@S0^T) + tril(exp(cum_t-cum_s)*(U@V^T)) @ G; gate; bf16 out
// ---------------------------------------------------------------------------
__global__ __launch_bounds__(256) void passB(
    const float* __restrict__ proj, const u16* __restrict__ U,
    const u16* __restrict__ V, const u16* __restrict__ Gt,
    const float* __restrict__ cumA, const float* __restrict__ S,
    const float* __restrict__ Dvec, u16* __restrict__ yz) {
  const int c = blockIdx.x >> 5, h = blockIdx.x & 31;
  const int c0 = c * CL;
  const int tid = threadIdx.x;
  const int w = tid >> 6, lane = tid & 63;
  const int wr = w >> 1, wc = w & 1;
  const int fr = lane & 15, sl = lane >> 4;
  __shared__ u16 Ul[64][168];
  __shared__ u16 BB[64][168];
  __shared__ u16 Ml[64][72];
  __shared__ u16 Gl[64][72];
  __shared__ float cums[64], ecum[64];

  const u16* Us = U + ((size_t)h * L_SEQ + c0) * NS;
  for (int i = tid; i < 1280; i += 256) {
    int r = i / 20, ch = i % 20;
    *(uint4*)&Ul[r][ch * 8] = *(const uint4*)(Us + (size_t)r * NS + ch * 8);
  }
  {
    const float* S0 = S + (size_t)(c * NH + h) * HD * NS;
    int r = tid >> 2, q4 = tid & 3;
#pragma unroll
    for (int i = 0; i < 10; ++i) {
      int ch = q4 * 10 + i;
      float4 f = *(const float4*)(S0 + (size_t)r * NS + ch * 4);
      u32 lo = (u32)f2bf(f.x) | ((u32)f2bf(f.y) << 16);
      u32 hi = (u32)f2bf(f.z) | ((u32)f2bf(f.w) << 16);
      *(u32*)&BB[r][ch * 4] = lo;
      *(u32*)&BB[r][ch * 4 + 2] = hi;
    }
  }
  if (tid < 64) {
    float cv = cumA[(size_t)h * L_SEQ + c0 + tid];
    cums[tid] = cv;
    ecum[tid] = expf(cv);
  }
  __syncthreads();

  f32x4 acc[2][2] = {};
#pragma unroll
  for (int ks = 0; ks < 5; ++ks) {
    bf16x8 a0 = *(const bf16x8*)&Ul[wr * 32 + fr][ks * 32 + sl * 8];
    bf16x8 a1 = *(const bf16x8*)&Ul[wr * 32 + 16 + fr][ks * 32 + sl * 8];
    bf16x8 b0 = *(const bf16x8*)&BB[wc * 32 + fr][ks * 32 + sl * 8];
    bf16x8 b1 = *(const bf16x8*)&BB[wc * 32 + 16 + fr][ks * 32 + sl * 8];
    acc[0][0] = __builtin_amdgcn_mfma_f32_16x16x32_bf16(a0, b0, acc[0][0], 0, 0, 0);
    acc[0][1] = __builtin_amdgcn_mfma_f32_16x16x32_bf16(a0, b1, acc[0][1], 0, 0, 0);
    acc[1][0] = __builtin_amdgcn_mfma_f32_16x16x32_bf16(a1, b0, acc[1][0], 0, 0, 0);
    acc[1][1] = __builtin_amdgcn_mfma_f32_16x16x32_bf16(a1, b1, acc[1][1], 0, 0, 0);
  }
#pragma unroll
  for (int fi = 0; fi < 2; ++fi)
#pragma unroll
    for (int fj = 0; fj < 2; ++fj)
#pragma unroll
      for (int r = 0; r < 4; ++r)
        acc[fi][fj][r] *= ecum[wr * 32 + fi * 16 + sl * 4 + r];
  __syncthreads();

  const u16* Vs = V + ((size_t)h * L_SEQ + c0) * NS;
  for (int i = tid; i < 1280; i += 256) {
    int r = i / 20, ch = i % 20;
    *(uint4*)&BB[r][ch * 8] = *(const uint4*)(Vs + (size_t)r * NS + ch * 8);
  }
  const u16* Gs = Gt + ((size_t)h * NC + c) * HD * CL;
  for (int i = tid; i < 512; i += 256) {
    int p = i >> 3, ch = i & 7;
    *(uint4*)&Gl[p][ch * 8] = *(const uint4*)(Gs + (size_t)p * CL + ch * 8);
  }
  __syncthreads();

  f32x4 pac[2][2] = {};
#pragma unroll
  for (int ks = 0; ks < 5; ++ks) {
    bf16x8 a0 = *(const bf16x8*)&Ul[wr * 32 + fr][ks * 32 + sl * 8];
    bf16x8 a1 = *(const bf16x8*)&Ul[wr * 32 + 16 + fr][ks * 32 + sl * 8];
    bf16x8 b0 = *(const bf16x8*)&BB[wc * 32 + fr][ks * 32 + sl * 8];
    bf16x8 b1 = *(const bf16x8*)&BB[wc * 32 + 16 + fr][ks * 32 + sl * 8];
    pac[0][0] = __builtin_amdgcn_mfma_f32_16x16x32_bf16(a0, b0, pac[0][0], 0, 0, 0);
    pac[0][1] = __builtin_amdgcn_mfma_f32_16x16x32_bf16(a0, b1, pac[0][1], 0, 0, 0);
    pac[1][0] = __builtin_amdgcn_mfma_f32_16x16x32_bf16(a1, b0, pac[1][0], 0, 0, 0);
    pac[1][1] = __builtin_amdgcn_mfma_f32_16x16x32_bf16(a1, b1, pac[1][1], 0, 0, 0);
  }
#pragma unroll
  for (int fi = 0; fi < 2; ++fi)
#pragma unroll
    for (int fj = 0; fj < 2; ++fj)
#pragma unroll
      for (int r = 0; r < 4; ++r) {
        int t = wr * 32 + fi * 16 + sl * 4 + r;
        int ss = wc * 32 + fj * 16 + fr;
        float m = (ss <= t) ? expf(cums[t] - cums[ss]) * pac[fi][fj][r] : 0.f;
        Ml[t][ss] = f2bf(m);
      }
  __syncthreads();

#pragma unroll
  for (int ks = 0; ks < 2; ++ks) {
    bf16x8 a0 = *(const bf16x8*)&Ml[wr * 32 + fr][ks * 32 + sl * 8];
    bf16x8 a1 = *(const bf16x8*)&Ml[wr * 32 + 16 + fr][ks * 32 + sl * 8];
    bf16x8 b0 = *(const bf16x8*)&Gl[wc * 32 + fr][ks * 32 + sl * 8];
    bf16x8 b1 = *(const bf16x8*)&Gl[wc * 32 + 16 + fr][ks * 32 + sl * 8];
    acc[0][0] = __builtin_amdgcn_mfma_f32_16x16x32_bf16(a0, b0, acc[0][0], 0, 0, 0);
    acc[0][1] = __builtin_amdgcn_mfma_f32_16x16x32_bf16(a0, b1, acc[0][1], 0, 0, 0);
    acc[1][0] = __builtin_amdgcn_mfma_f32_16x16x32_bf16(a1, b0, acc[1][0], 0, 0, 0);
    acc[1][1] = __builtin_amdgcn_mfma_f32_16x16x32_bf16(a1, b1, acc[1][1], 0, 0, 0);
  }

  const float Dh = Dvec[h];
#pragma unroll
  for (int fi = 0; fi < 2; ++fi)
#pragma unroll
    for (int fj = 0; fj < 2; ++fj)
#pragma unroll
      for (int r = 0; r < 4; ++r) {
        int t = wr * 32 + fi * 16 + sl * 4 + r;
        int p = wc * 32 + fj * 16 + fr;
        int l = c0 + t;
        float x = proj[(size_t)l * NPROJ + OFF_X + h * HD + p];
        float z = proj[(size_t)l * NPROJ + OFF_Z + h * HD + p];
        float y = acc[fi][fj][r] + Dh * x;
        float sg = z / (1.f + expf(-z));
        yz[(size_t)l * DINNER + h * HD + p] = f2bf(y * sg);
      }
}

// ---------------------------------------------------------------------------
extern "C" void kernel_launch(void* const* d_in, const int* in_sizes, int n_in,
                              void* d_out, int out_size, void* d_ws, size_t ws_size,
                              hipStream_t stream) {
  const float* u       = (const float*)d_in[0];
  const float* w_in    = (const float*)d_in[1];
  const float* w_out   = (const float*)d_in[2];
  const float* dt_bias = (const float*)d_in[3];
  const float* Dvec    = (const float*)d_in[4];
  float* out = (float*)d_out;

  float* ws = (float*)d_ws;
  float* proj   = ws;                          // 4,587,520 f
  float* dtA    = proj + 4587520;              // 32768
  float* lnaA   = dtA + 32768;
  float* betaA  = lnaA + 32768;
  float* gammaA = betaA + 32768;
  float* cumA   = gammaA + 32768;
  float* adec   = cumA + 32768;                // 512
  float* angP   = adec + 512;                  // 32768
  float* Sbuf   = angP + 32768;                // 5,242,880 f
  u16*   Gtb    = (u16*)(Sbuf + 5242880);      // 2,097,152 u16
  u16*   Ubuf   = Gtb + 2097152;               // 5,242,880 u16
  u16*   Vbuf   = Ubuf + 5242880;              // 5,242,880 u16
  u16*   yzb    = Vbuf + 5242880;              // 2,097,152 u16
  // overlays in Sbuf (disjoint lifetimes):
  u16*   ub   = (u16*)Sbuf;                    // epoch 1 (until gemm1)
  u16*   wib  = ub + 1048576;
  float* rcb  = Sbuf;                          // epoch 2 (theta -> prep_uvg)
  float* rsb  = rcb + 1048576;
  u16*   wob  = (u16*)Sbuf;                    // epoch 4 (after passB)

  // 0. inputs -> bf16
  cvt_bf16<<<(1048576 / 8 + 255) / 256, 256, 0, stream>>>(u, ub, 1048576 / 8);
  cvt_bf16<<<(4587520 / 8 + 255) / 256, 256, 0, stream>>>(w_in, wib, 4587520 / 8);

  // 1. proj = u @ w_in^T
  gemm_bf16<128, 128><<<dim3(NPROJ / 128, L_SEQ / 128), 256, 0, stream>>>(
      ub, wib, proj, NPROJ, DMODEL);

  // 2. scalars (+ angP pack)
  prep_scalars<<<(L_SEQ * NH) / 256, 256, 0, stream>>>(
      proj, dt_bias, dtA, lnaA, betaA, gammaA, angP);

  // 3. theta -> rc, rs
  theta_scan<<<NH * RR, 256, 0, stream>>>(angP, dtA, rcb, rsb);

  // 4. U, V, Gt, cums
  prep_uvg<<<NH * NC, 256, 0, stream>>>(
      proj, betaA, gammaA, lnaA, rcb, rsb, Ubuf, Vbuf, Gtb, cumA, adec);

  // 5. chunk-local finals
  passA<<<NC * NH, 256, 0, stream>>>(Vbuf, Gtb, cumA, Sbuf);

  // 6. cross-chunk combine
  combine<<<(NH * HD * NS + 255) / 256, 256, 0, stream>>>(Sbuf, adec);

  // 7. Y + gate -> yz bf16
  passB<<<NC * NH, 256, 0, stream>>>(
      proj, Ubuf, Vbuf, Gtb, cumA, Sbuf, Dvec, yzb);

  // 8. w_out -> bf16 (Sbuf region dead now)
  cvt_bf16<<<(2097152 / 8 + 255) / 256, 256, 0, stream>>>(w_out, wob, 2097152 / 8);

  // 9. out = yz @ w_out^T
  gemm_bf16<64, 64><<<dim3(DMODEL / 64, L_SEQ / 64), 256, 0, stream>>>(
      yzb, wob, out, DMODEL, DINNER);
}

// Round 6
// 133.948 us; speedup vs baseline: 3.5888x; 1.1247x over previous
//
#include <hip/hip_runtime.h>
#include <math.h>

#define L_SEQ   1024
#define DMODEL  1024
#define DINNER  2048
#define NH      32
#define HD      64
#define NS      160     // augmented state dim = 32 rot-re + 32 rot-im + 96 plain
#define RR      32      // rotary dims
#define NPROJ   4480
#define OFF_Z   0
#define OFF_X   2048
#define OFF_B   4096
#define OFF_C   4224
#define OFF_DT  4352
#define OFF_A   4384
#define OFF_TR  4416
#define OFF_ANG 4448
#define NC      16
#define CL      64
#define PIF     3.14159265358979323846f

typedef __attribute__((ext_vector_type(8))) short bf16x8;
typedef __attribute__((ext_vector_type(4))) float f32x4;
typedef unsigned int u32;
typedef unsigned short u16;

__device__ __forceinline__ float softplusf(float x) {
  return (x > 20.f) ? x : log1pf(expf(x));
}
__device__ __forceinline__ u16 f2bf(float f) {
  u32 u = __float_as_uint(f);
  u32 r = (u + 0x7FFFu + ((u >> 16) & 1u)) >> 16;
  return (u16)r;
}
__device__ __forceinline__ float bf2f(u16 v) {
  return __uint_as_float(((u32)v) << 16);
}

// global->LDS direct DMA, 16B per lane (m97 staging path).
__device__ __forceinline__ void gload_lds16(const u16* g, u16* l) {
  __builtin_amdgcn_global_load_lds(
      (const __attribute__((address_space(1))) u32*)(unsigned long long)(const void*)g,
      (__attribute__((address_space(3))) u32*)(unsigned long long)(void*)l, 16, 0, 0);
}

// ---------------------------------------------------------------------------
// cvt2: f32 -> bf16 (RNE) for two buffers in one launch. 8 elems/thread.
// ---------------------------------------------------------------------------
__global__ __launch_bounds__(256) void cvt2_bf16(
    const float* __restrict__ s0, u16* __restrict__ d0, int q0,
    const float* __restrict__ s1, u16* __restrict__ d1, int q1) {
  int i = blockIdx.x * 256 + threadIdx.x;
  const float* s; u16* d; int j;
  if (i < q0) { s = s0; d = d0; j = i; }
  else { j = i - q0; if (j >= q1) return; s = s1; d = d1; }
  const float4* s4 = (const float4*)s;
  float4 a = s4[2 * j], b = s4[2 * j + 1];
  union { u16 h[8]; uint4 v; } o;
  o.h[0] = f2bf(a.x); o.h[1] = f2bf(a.y); o.h[2] = f2bf(a.z); o.h[3] = f2bf(a.w);
  o.h[4] = f2bf(b.x); o.h[5] = f2bf(b.y); o.h[6] = f2bf(b.z); o.h[7] = f2bf(b.w);
  ((uint4*)d)[j] = o.v;
}

// ---------------------------------------------------------------------------
// bf16 MFMA GEMM, m97 structure (round-4, verified): C = A . B^T, fp32 out.
// ---------------------------------------------------------------------------
template <int BM, int BN>
__global__ __launch_bounds__(256) void gemm_bf16(
    const u16* __restrict__ A, const u16* __restrict__ B,
    float* __restrict__ C, int N, int K) {
  constexpr int BK = 32;
  constexpr int WM = BM / 2, WN = BN / 2;
  constexpr int MF = WM / 16, NF = WN / 16;
  constexpr int CA = BM / 64;
  constexpr int CB = BN / 64;
  __shared__ u16 lds[(BM + BN) * BK];

  const int bm = blockIdx.y * BM, bn = blockIdx.x * BN;
  const int tid = threadIdx.x, w = tid >> 6, lane = tid & 63;
  const int wr = w >> 1, wc = w & 1;
  const int fr = lane & 15, sl = lane >> 4;
  const int lrow = lane >> 2, lslot = (lane & 3) * 8;

  const u16* gA[CA]; u16* lA[CA];
#pragma unroll
  for (int j = 0; j < CA; ++j) {
    int ca = w * CA + j;
    gA[j] = A + (size_t)(bm + ca * 16 + lrow) * K + lslot;
    lA[j] = lds + ca * 512;
  }
  const u16* gB[CB]; u16* lB[CB];
#pragma unroll
  for (int j = 0; j < CB; ++j) {
    int cb = w * CB + j;
    gB[j] = B + (size_t)(bn + cb * 16 + lrow) * K + lslot;
    lB[j] = lds + BM * 32 + cb * 512;
  }

  const u16* aptr[MF]; const u16* bptr[NF];
#pragma unroll
  for (int i = 0; i < MF; ++i)
    aptr[i] = lds + (wr * WM + i * 16 + fr) * 32 + sl * 8;
#pragma unroll
  for (int j = 0; j < NF; ++j)
    bptr[j] = lds + BM * 32 + (wc * WN + j * 16 + fr) * 32 + sl * 8;

  f32x4 acc[MF][NF] = {};
  const int iters = K / BK;

#pragma unroll
  for (int j = 0; j < CA; ++j) gload_lds16(gA[j], lA[j]);
#pragma unroll
  for (int j = 0; j < CB; ++j) gload_lds16(gB[j], lB[j]);

  for (int it = 0; it < iters; ++it) {
    __syncthreads();
    bf16x8 af[MF], bfv[NF];
#pragma unroll
    for (int i = 0; i < MF; ++i) af[i] = *(const bf16x8*)aptr[i];
#pragma unroll
    for (int j = 0; j < NF; ++j) bfv[j] = *(const bf16x8*)bptr[j];
    __syncthreads();
    if (it + 1 < iters) {
#pragma unroll
      for (int j = 0; j < CA; ++j) gload_lds16(gA[j] + (it + 1) * BK, lA[j]);
#pragma unroll
      for (int j = 0; j < CB; ++j) gload_lds16(gB[j] + (it + 1) * BK, lB[j]);
    }
#pragma unroll
    for (int i = 0; i < MF; ++i)
#pragma unroll
      for (int j = 0; j < NF; ++j)
        acc[i][j] = __builtin_amdgcn_mfma_f32_16x16x32_bf16(
            af[i], bfv[j], acc[i][j], 0, 0, 0);
  }

#pragma unroll
  for (int i = 0; i < MF; ++i) {
    int rb = bm + wr * WM + i * 16 + sl * 4;
#pragma unroll
    for (int j = 0; j < NF; ++j) {
      int cb = bn + wc * WN + j * 16 + fr;
#pragma unroll
      for (int r = 0; r < 4; ++r)
        C[(size_t)(rb + r) * N + cb] = acc[i][j][r];
    }
  }
}

// ---------------------------------------------------------------------------
// prep_scalars_cvt: blocks <1024 convert w_out f32->bf16; blocks >=1024 do
// per-(l,h) scalars: dt, ln(alpha), beta, gamma, angP = tanh(ang)*pi.
// ---------------------------------------------------------------------------
__global__ __launch_bounds__(256) void prep_scalars_cvt(
    const float* __restrict__ proj, const float* __restrict__ dt_bias,
    float* __restrict__ dtA, float* __restrict__ lnaA,
    float* __restrict__ betaA, float* __restrict__ gammaA,
    float* __restrict__ angP,
    const float* __restrict__ wsrc, u16* __restrict__ wdst) {
  const int b = blockIdx.x;
  if (b < 1024) {                      // w_out: 2097152 elems = 262144 quads
    int j = b * 256 + threadIdx.x;
    const float4* s4 = (const float4*)wsrc;
    float4 a = s4[2 * j], bb = s4[2 * j + 1];
    union { u16 h[8]; uint4 v; } o;
    o.h[0] = f2bf(a.x); o.h[1] = f2bf(a.y); o.h[2] = f2bf(a.z); o.h[3] = f2bf(a.w);
    o.h[4] = f2bf(bb.x); o.h[5] = f2bf(bb.y); o.h[6] = f2bf(bb.z); o.h[7] = f2bf(bb.w);
    ((uint4*)wdst)[j] = o.v;
    return;
  }
  int idx = (b - 1024) * 256 + threadIdx.x;   // l*32+h
  int h = idx & 31, l = idx >> 5;
  const float* prow = proj + (size_t)l * NPROJ;
  float dt = softplusf(prow[OFF_DT + h] + dt_bias[h]);
  float Apos = fmaxf(softplusf(prow[OFF_A + h]), 1e-4f);
  float tr = 1.f / (1.f + expf(-prow[OFF_TR + h]));
  float lna = -Apos * dt;
  float alpha = expf(lna);
  dtA[idx] = dt;
  lnaA[idx] = lna;
  betaA[idx] = (1.f - tr) * dt * alpha;
  gammaA[idx] = tr * dt;
  angP[idx] = tanhf(prow[OFF_ANG + h]) * PIF;
}

// ---------------------------------------------------------------------------
// theta_scan: cumsum over L of angP*dt -> rc=cos, rs=sin. Block per (h,r).
// ---------------------------------------------------------------------------
__global__ __launch_bounds__(256) void theta_scan(
    const float* __restrict__ angP, const float* __restrict__ dtA,
    float* __restrict__ rc, float* __restrict__ rs) {
  const int h = blockIdx.x >> 5;
  const int r = blockIdx.x & 31;
  const int tid = threadIdx.x;
  __shared__ float ldssc[256];

  float csum[4];
  float run = 0.f;
#pragma unroll
  for (int i = 0; i < 4; ++i) {
    int l = tid * 4 + i;
    run += angP[l * NH + r] * dtA[l * NH + h];
    csum[i] = run;
  }
  ldssc[tid] = run;
  __syncthreads();
  for (int off = 1; off < 256; off <<= 1) {
    float t = (tid >= off) ? ldssc[tid - off] : 0.f;
    __syncthreads();
    ldssc[tid] += t;
    __syncthreads();
  }
  float excl = ldssc[tid] - run;
#pragma unroll
  for (int i = 0; i < 4; ++i) {
    int l = tid * 4 + i;
    float th = excl + csum[i];
    size_t o = ((size_t)l * NH + h) * RR + r;
    rc[o] = cosf(th);
    rs[o] = sinf(th);
  }
}

// ---------------------------------------------------------------------------
// uvgA: fused prep_uvg + passA. Block per (h,c).
//  ph0: waves0-2 stage xs; wave3 cumA scan -> wsc/bet/gam
//  ph1: G build (lane=p): Gt global raw + Gw LDS pre-scaled by wsc
//  ph2: U/V build lane-per-n (global) + Vl LDS
//  ph3: transpose Vl -> Vt
//  ph4: MFMA F[p,n] = sum_s Gw[p,s]*Vt[n,s]; write S (bf16)
// LDS arena 54784B: [Gw 9216][wsc/bet/gam 1024][R: xs 16640 | Vl 21504][Vt 23040]
// ---------------------------------------------------------------------------
__global__ __launch_bounds__(256) void uvgA(
    const float* __restrict__ proj, const float* __restrict__ betaA,
    const float* __restrict__ gammaA, const float* __restrict__ lnaA,
    const float* __restrict__ rc, const float* __restrict__ rs,
    u16* __restrict__ U, u16* __restrict__ V, u16* __restrict__ Gt,
    float* __restrict__ cumA, float* __restrict__ adec,
    u16* __restrict__ S) {
  const int h = blockIdx.x >> 4, c = blockIdx.x & 15;
  const int c0 = c * CL;
  const int tid = threadIdx.x;
  const int w = tid >> 6, lane = tid & 63;

  __shared__ __attribute__((aligned(16))) char smem[54784];
  u16 (*Gw)[72]   = (u16(*)[72])(smem);              // [64][72]
  float* wsc      = (float*)(smem + 9216);           // [64]
  float* bet      = (float*)(smem + 9472);           // [64]
  float* gam      = (float*)(smem + 9728);           // [64]
  float (*xs)[64] = (float(*)[64])(smem + 10240);    // [65][64]
  u16 (*Vl)[168]  = (u16(*)[168])(smem + 10240);     // [64][168] (aliases xs)
  u16 (*Vt)[72]   = (u16(*)[72])(smem + 31744);      // [160][72]

  // ph0
  if (w < 3) {
    for (int i = tid; i < 65 * 16; i += 192) {
      int r = i >> 4, c4 = i & 15;
      int l = c0 - 1 + r;
      float4 v = {0.f, 0.f, 0.f, 0.f};
      if (l >= 0)
        v = *(const float4*)(proj + (size_t)l * NPROJ + OFF_X + h * HD + c4 * 4);
      *(float4*)&xs[r][c4 * 4] = v;
    }
  } else {
    const int t = lane;
    float v = lnaA[(c0 + t) * NH + h];
#pragma unroll
    for (int k = 1; k < 64; k <<= 1) {
      int src = t - k;
      float o = __shfl(v, src < 0 ? 0 : src);
      if (t >= k) v += o;
    }
    cumA[(size_t)h * L_SEQ + c0 + t] = v;
    if (t == 63) adec[h * NC + c] = expf(v);
    float c63 = __shfl(v, 63);
    wsc[t] = expf(c63 - v);
    bet[t] = betaA[(c0 + t) * NH + h];
    gam[t] = gammaA[(c0 + t) * NH + h];
  }
  __syncthreads();

  // ph1: G build, lane = p, wave covers s = w*16..w*16+15
  {
    const int p = lane;
    union { u16 hh[16]; uint4 q[2]; } og, ow;
    float xprev = xs[w * 16][p];
#pragma unroll
    for (int i = 0; i < 16; ++i) {
      int s = w * 16 + i;
      float xcur = xs[s + 1][p];
      float g = bet[s] * xprev + gam[s] * xcur;
      og.hh[i] = f2bf(g);
      ow.hh[i] = f2bf(g * wsc[s]);
      xprev = xcur;
    }
    uint4* gdst = (uint4*)(Gt + (((size_t)h * NC + c) * HD + p) * CL + w * 16);
    gdst[0] = og.q[0];
    gdst[1] = og.q[1];
    *(uint4*)&Gw[p][w * 16] = ow.q[0];
    *(uint4*)&Gw[p][w * 16 + 8] = ow.q[1];
  }
  __syncthreads();       // xs dead beyond this point; Vl may be written

  // ph2: U/V build lane-per-n
  if (tid < 160) {
    const int n = tid;
    const int idxB = (n < 64) ? (n & 31) : (n - 32);
    const bool is_re = (n < 32);
    const bool has_rot = (n < 64);
    for (int ss = 0; ss < 64; ++ss) {
      int l = c0 + ss;
      const float* prow = proj + (size_t)l * NPROJ;
      float Bv = prow[OFF_B + idxB];
      float Cv = prow[OFF_C + idxB];
      if (has_rot) {
        float rv = is_re ? rc[((size_t)l * NH + h) * RR + idxB]
                         : rs[((size_t)l * NH + h) * RR + idxB];
        Bv *= rv; Cv *= rv;
      }
      u16 bb = f2bf(Bv);
      U[((size_t)h * L_SEQ + l) * NS + n] = f2bf(Cv);
      V[((size_t)h * L_SEQ + l) * NS + n] = bb;
      Vl[ss][n] = bb;
    }
  }
  __syncthreads();

  // ph3: transpose Vl -> Vt
  if (tid < 160) {
    int n = tid;
#pragma unroll
    for (int s2 = 0; s2 < 32; ++s2) {
      u32 lo = Vl[2 * s2][n], hi = Vl[2 * s2 + 1][n];
      *(u32*)&Vt[n][2 * s2] = lo | (hi << 16);
    }
  }
  __syncthreads();

  // ph4: MFMA, write chunk finals (bf16)
  const int wr = w >> 1, wc = w & 1;
  const int fr = lane & 15, sl = lane >> 4;
  f32x4 acc[2][5] = {};
#pragma unroll
  for (int ks = 0; ks < 2; ++ks) {
    bf16x8 a0 = *(const bf16x8*)&Gw[wr * 32 + fr][ks * 32 + sl * 8];
    bf16x8 a1 = *(const bf16x8*)&Gw[wr * 32 + 16 + fr][ks * 32 + sl * 8];
    bf16x8 bv[5];
#pragma unroll
    for (int fj = 0; fj < 5; ++fj)
      bv[fj] = *(const bf16x8*)&Vt[wc * 80 + fj * 16 + fr][ks * 32 + sl * 8];
#pragma unroll
    for (int fj = 0; fj < 5; ++fj) {
      acc[0][fj] = __builtin_amdgcn_mfma_f32_16x16x32_bf16(a0, bv[fj], acc[0][fj], 0, 0, 0);
      acc[1][fj] = __builtin_amdgcn_mfma_f32_16x16x32_bf16(a1, bv[fj], acc[1][fj], 0, 0, 0);
    }
  }
  u16* Fb = S + (size_t)(c * NH + h) * HD * NS;
#pragma unroll
  for (int fi = 0; fi < 2; ++fi)
#pragma unroll
    for (int fj = 0; fj < 5; ++fj)
#pragma unroll
      for (int r = 0; r < 4; ++r) {
        int p = wr * 32 + fi * 16 + sl * 4 + r;
        int n = wc * 80 + fj * 16 + fr;
        Fb[(size_t)p * NS + n] = f2bf(acc[fi][fj][r]);
      }
}

// ---------------------------------------------------------------------------
// combine: sequential over 16 chunks per (h,p,n); finals -> inits. S is bf16;
// running accumulator F stays fp32 in-register.
// ---------------------------------------------------------------------------
__global__ __launch_bounds__(256) void combine(
    u16* __restrict__ S, const float* __restrict__ adec) {
  const int idx = blockIdx.x * 256 + threadIdx.x;
  if (idx >= NH * HD * NS) return;
  const int n = idx % NS;
  const int rem = idx / NS;
  const int p = rem & 63;
  const int h = rem >> 6;
  float F = 0.f;
  for (int c = 0; c < NC; ++c) {
    size_t off = ((size_t)(c * NH + h) * HD + p) * NS + n;
    float sv = bf2f(S[off]);
    S[off] = f2bf(F);
    F = fmaf(F, adec[h * NC + c], sv);
  }
}

// ---------------------------------------------------------------------------
// passB: Y = ecum*(U@S0^T) + tril(exp(cum_t-cum_s)*(U@V^T)) @ G; gate; bf16 out
// ---------------------------------------------------------------------------
__global__ __launch_bounds__(256) void passB(
    const float* __restrict__ proj, const u16* __restrict__ U,
    const u16* __restrict__ V, const u16* __restrict__ Gt,
    const float* __restrict__ cumA, const u16* __restrict__ S,
    const float* __restrict__ Dvec, u16* __restrict__ yz) {
  const int c = blockIdx.x >> 5, h = blockIdx.x & 31;
  const int c0 = c * CL;
  const int tid = threadIdx.x;
  const int w = tid >> 6, lane = tid & 63;
  const int wr = w >> 1, wc = w & 1;
  const int fr = lane & 15, sl = lane >> 4;
  __shared__ u16 Ul[64][168];
  __shared__ u16 BB[64][168];
  __shared__ u16 Ml[64][72];
  __shared__ u16 Gl[64][72];
  __shared__ float cums[64], ecum[64];

  const u16* Us = U + ((size_t)h * L_SEQ + c0) * NS;
  for (int i = tid; i < 1280; i += 256) {
    int r = i / 20, ch = i % 20;
    *(uint4*)&Ul[r][ch * 8] = *(const uint4*)(Us + (size_t)r * NS + ch * 8);
  }
  {
    const u16* S0 = S + (size_t)(c * NH + h) * HD * NS;
    for (int i = tid; i < 1280; i += 256) {
      int r = i / 20, ch = i % 20;
      *(uint4*)&BB[r][ch * 8] = *(const uint4*)(S0 + (size_t)r * NS + ch * 8);
    }
  }
  if (tid < 64) {
    float cv = cumA[(size_t)h * L_SEQ + c0 + tid];
    cums[tid] = cv;
    ecum[tid] = expf(cv);
  }
  __syncthreads();

  f32x4 acc[2][2] = {};
#pragma unroll
  for (int ks = 0; ks < 5; ++ks) {
    bf16x8 a0 = *(const bf16x8*)&Ul[wr * 32 + fr][ks * 32 + sl * 8];
    bf16x8 a1 = *(const bf16x8*)&Ul[wr * 32 + 16 + fr][ks * 32 + sl * 8];
    bf16x8 b0 = *(const bf16x8*)&BB[wc * 32 + fr][ks * 32 + sl * 8];
    bf16x8 b1 = *(const bf16x8*)&BB[wc * 32 + 16 + fr][ks * 32 + sl * 8];
    acc[0][0] = __builtin_amdgcn_mfma_f32_16x16x32_bf16(a0, b0, acc[0][0], 0, 0, 0);
    acc[0][1] = __builtin_amdgcn_mfma_f32_16x16x32_bf16(a0, b1, acc[0][1], 0, 0, 0);
    acc[1][0] = __builtin_amdgcn_mfma_f32_16x16x32_bf16(a1, b0, acc[1][0], 0, 0, 0);
    acc[1][1] = __builtin_amdgcn_mfma_f32_16x16x32_bf16(a1, b1, acc[1][1], 0, 0, 0);
  }
#pragma unroll
  for (int fi = 0; fi < 2; ++fi)
#pragma unroll
    for (int fj = 0; fj < 2; ++fj)
#pragma unroll
      for (int r = 0; r < 4; ++r)
        acc[fi][fj][r] *= ecum[wr * 32 + fi * 16 + sl * 4 + r];
  __syncthreads();

  const u16* Vs = V + ((size_t)h * L_SEQ + c0) * NS;
  for (int i = tid; i < 1280; i += 256) {
    int r = i / 20, ch = i % 20;
    *(uint4*)&BB[r][ch * 8] = *(const uint4*)(Vs + (size_t)r * NS + ch * 8);
  }
  const u16* Gs = Gt + ((size_t)h * NC + c) * HD * CL;
  for (int i = tid; i < 512; i += 256) {
    int p = i >> 3, ch = i & 7;
    *(uint4*)&Gl[p][ch * 8] = *(const uint4*)(Gs + (size_t)p * CL + ch * 8);
  }
  __syncthreads();

  f32x4 pac[2][2] = {};
#pragma unroll
  for (int ks = 0; ks < 5; ++ks) {
    bf16x8 a0 = *(const bf16x8*)&Ul[wr * 32 + fr][ks * 32 + sl * 8];
    bf16x8 a1 = *(const bf16x8*)&Ul[wr * 32 + 16 + fr][ks * 32 + sl * 8];
    bf16x8 b0 = *(const bf16x8*)&BB[wc * 32 + fr][ks * 32 + sl * 8];
    bf16x8 b1 = *(const bf16x8*)&BB[wc * 32 + 16 + fr][ks * 32 + sl * 8];
    pac[0][0] = __builtin_amdgcn_mfma_f32_16x16x32_bf16(a0, b0, pac[0][0], 0, 0, 0);
    pac[0][1] = __builtin_amdgcn_mfma_f32_16x16x32_bf16(a0, b1, pac[0][1], 0, 0, 0);
    pac[1][0] = __builtin_amdgcn_mfma_f32_16x16x32_bf16(a1, b0, pac[1][0], 0, 0, 0);
    pac[1][1] = __builtin_amdgcn_mfma_f32_16x16x32_bf16(a1, b1, pac[1][1], 0, 0, 0);
  }
#pragma unroll
  for (int fi = 0; fi < 2; ++fi)
#pragma unroll
    for (int fj = 0; fj < 2; ++fj)
#pragma unroll
      for (int r = 0; r < 4; ++r) {
        int t = wr * 32 + fi * 16 + sl * 4 + r;
        int ss = wc * 32 + fj * 16 + fr;
        float m = (ss <= t) ? expf(cums[t] - cums[ss]) * pac[fi][fj][r] : 0.f;
        Ml[t][ss] = f2bf(m);
      }
  __syncthreads();

#pragma unroll
  for (int ks = 0; ks < 2; ++ks) {
    bf16x8 a0 = *(const bf16x8*)&Ml[wr * 32 + fr][ks * 32 + sl * 8];
    bf16x8 a1 = *(const bf16x8*)&Ml[wr * 32 + 16 + fr][ks * 32 + sl * 8];
    bf16x8 b0 = *(const bf16x8*)&Gl[wc * 32 + fr][ks * 32 + sl * 8];
    bf16x8 b1 = *(const bf16x8*)&Gl[wc * 32 + 16 + fr][ks * 32 + sl * 8];
    acc[0][0] = __builtin_amdgcn_mfma_f32_16x16x32_bf16(a0, b0, acc[0][0], 0, 0, 0);
    acc[0][1] = __builtin_amdgcn_mfma_f32_16x16x32_bf16(a0, b1, acc[0][1], 0, 0, 0);
    acc[1][0] = __builtin_amdgcn_mfma_f32_16x16x32_bf16(a1, b0, acc[1][0], 0, 0, 0);
    acc[1][1] = __builtin_amdgcn_mfma_f32_16x16x32_bf16(a1, b1, acc[1][1], 0, 0, 0);
  }

  const float Dh = Dvec[h];
#pragma unroll
  for (int fi = 0; fi < 2; ++fi)
#pragma unroll
    for (int fj = 0; fj < 2; ++fj)
#pragma unroll
      for (int r = 0; r < 4; ++r) {
        int t = wr * 32 + fi * 16 + sl * 4 + r;
        int p = wc * 32 + fj * 16 + fr;
        int l = c0 + t;
        float x = proj[(size_t)l * NPROJ + OFF_X + h * HD + p];
        float z = proj[(size_t)l * NPROJ + OFF_Z + h * HD + p];
        float y = acc[fi][fj][r] + Dh * x;
        float sg = z / (1.f + expf(-z));
        yz[(size_t)l * DINNER + h * HD + p] = f2bf(y * sg);
      }
}

// ---------------------------------------------------------------------------
extern "C" void kernel_launch(void* const* d_in, const int* in_sizes, int n_in,
                              void* d_out, int out_size, void* d_ws, size_t ws_size,
                              hipStream_t stream) {
  const float* u       = (const float*)d_in[0];
  const float* w_in    = (const float*)d_in[1];
  const float* w_out   = (const float*)d_in[2];
  const float* dt_bias = (const float*)d_in[3];
  const float* Dvec    = (const float*)d_in[4];
  float* out = (float*)d_out;

  float* ws = (float*)d_ws;
  float* proj   = ws;                          // 4,587,520 f
  float* dtA    = proj + 4587520;              // 32768
  float* lnaA   = dtA + 32768;
  float* betaA  = lnaA + 32768;
  float* gammaA = betaA + 32768;
  float* cumA   = gammaA + 32768;
  float* adec   = cumA + 32768;                // 512
  float* angP   = adec + 512;                  // 32768
  float* rcb    = angP + 32768;                // 1,048,576 (dedicated: uvgA
  float* rsb    = rcb + 1048576;               //  reads rc/rs AND writes S)
  u16*   Sb     = (u16*)(rsb + 1048576);       // 5,242,880 u16 (bf16 states)
  u16*   Gtb    = Sb + 5242880;                // 2,097,152 u16
  u16*   Ubuf   = Gtb + 2097152;               // 5,242,880 u16
  u16*   Vbuf   = Ubuf + 5242880;              // 5,242,880 u16
  u16*   yzb    = Vbuf + 5242880;              // 2,097,152 u16
  u16*   wob    = yzb + 2097152;               // 2,097,152 u16
  // epoch-1 overlay (dead before uvgA writes U/V):
  u16*   ub     = Ubuf;                        // 1,048,576 u16
  u16*   wib    = Ubuf + 1048576;              // 4,587,520 u16

  // 1. u + w_in -> bf16 (one launch)
  cvt2_bf16<<<(131072 + 573440) / 256, 256, 0, stream>>>(
      u, ub, 131072, w_in, wib, 573440);

  // 2. proj = u @ w_in^T
  gemm_bf16<128, 128><<<dim3(NPROJ / 128, L_SEQ / 128), 256, 0, stream>>>(
      ub, wib, proj, NPROJ, DMODEL);

  // 3. scalars + angP + w_out->bf16 (one launch)
  prep_scalars_cvt<<<1024 + 128, 256, 0, stream>>>(
      proj, dt_bias, dtA, lnaA, betaA, gammaA, angP, w_out, wob);

  // 4. theta -> rc, rs
  theta_scan<<<NH * RR, 256, 0, stream>>>(angP, dtA, rcb, rsb);

  // 5. fused U/V/Gt/cumA build + chunk-local finals
  uvgA<<<NH * NC, 256, 0, stream>>>(
      proj, betaA, gammaA, lnaA, rcb, rsb, Ubuf, Vbuf, Gtb, cumA, adec, Sb);

  // 6. cross-chunk combine (bf16 states)
  combine<<<(NH * HD * NS + 255) / 256, 256, 0, stream>>>(Sb, adec);

  // 7. Y + gate -> yz bf16
  passB<<<NC * NH, 256, 0, stream>>>(
      proj, Ubuf, Vbuf, Gtb, cumA, Sb, Dvec, yzb);

  // 8. out = yz @ w_out^T
  gemm_bf16<64, 64><<<dim3(DMODEL / 64, L_SEQ / 64), 256, 0, stream>>>(
      yzb, wob, out, DMODEL, DINNER);
}